// Round 7
// baseline (199.473 us; speedup 1.0000x reference)
//
#include <hip/hip_runtime.h>
#include <hip/hip_bf16.h>

constexpr int B_ = 2;
constexpr int T_ = 2048;
constexpr int C_ = 1024;
constexpr int H_ = 16;
constexpr int D_ = 64;
constexpr int M_ = B_ * T_;   // 4096 rows

typedef __attribute__((ext_vector_type(8))) short bf16x8;   // 8 bf16 = 4 VGPRs
typedef __attribute__((ext_vector_type(4))) float f32x4;
typedef const __attribute__((address_space(1))) void gaddr_t;
typedef __attribute__((address_space(3))) void laddr_t;

__device__ __forceinline__ unsigned short f2bf(float f) {   // fp32 -> bf16 RNE
    unsigned u = __float_as_uint(f);
    return (unsigned short)((u + 0x7fffu + ((u >> 16) & 1u)) >> 16);
}

union BF8 { bf16x8 v; __hip_bfloat162 h[4]; };

__device__ __forceinline__ bf16x8 cvt8(const float4 a, const float4 b) {
    BF8 r;
    r.h[0] = __float22bfloat162_rn(make_float2(a.x, a.y));
    r.h[1] = __float22bfloat162_rn(make_float2(a.z, a.w));
    r.h[2] = __float22bfloat162_rn(make_float2(b.x, b.y));
    r.h[3] = __float22bfloat162_rn(make_float2(b.z, b.w));
    return r.v;
}

// ---------------------------------------------------------------------------
// prep: z<4 -> W (K x N fp32) -> Wt (N x K bf16); z==4 -> x fp32 -> xb bf16.
// ---------------------------------------------------------------------------
__global__ __launch_bounds__(256)
void prep(const float* __restrict__ x, const float* __restrict__ Wq,
          const float* __restrict__ Wk, const float* __restrict__ Wv,
          const float* __restrict__ Wo, unsigned short* __restrict__ xb,
          unsigned short* __restrict__ wtb)
{
    const int z = blockIdx.z;
    const int tid = threadIdx.x;

    if (z == 4) {                                   // x cast: 256 blocks handle 1M float4
        const int base = (blockIdx.y * 16 + blockIdx.x) * 4096 + tid;
#pragma unroll
        for (int i = 0; i < 16; ++i) {
            const int idx = base + i * 256;
            float4 v = ((const float4*)x)[idx];
            union { __hip_bfloat162 h[2]; ushort4 u; } o;
            o.h[0] = __float22bfloat162_rn(make_float2(v.x, v.y));
            o.h[1] = __float22bfloat162_rn(make_float2(v.z, v.w));
            ((ushort4*)xb)[idx] = o.u;
        }
        return;
    }

    __shared__ float tile[64][65];
    const float* W = (z == 0) ? Wq : (z == 1) ? Wk : (z == 2) ? Wv : Wo;
    unsigned short* O = wtb + (size_t)z * C_ * C_;

    const int n0 = blockIdx.x * 64, k0 = blockIdx.y * 64;
    const int r = tid >> 4, c4 = (tid & 15) * 4;

#pragma unroll
    for (int i = 0; i < 4; ++i) {
        const int kk = i * 16 + r;
        float4 v = *(const float4*)(W + (size_t)(k0 + kk) * C_ + n0 + c4);
        tile[c4 + 0][kk] = v.x;
        tile[c4 + 1][kk] = v.y;
        tile[c4 + 2][kk] = v.z;
        tile[c4 + 3][kk] = v.w;
    }
    __syncthreads();
#pragma unroll
    for (int i = 0; i < 4; ++i) {
        const int nn = i * 16 + r;
        ushort4 o;
        o.x = f2bf(tile[nn][c4 + 0]);
        o.y = f2bf(tile[nn][c4 + 1]);
        o.z = f2bf(tile[nn][c4 + 2]);
        o.w = f2bf(tile[nn][c4 + 3]);
        *(ushort4*)(O + (size_t)(n0 + nn) * C_ + k0 + c4) = o;
    }
}

// ---------------------------------------------------------------------------
// Fused QKV GEMM v3 — 128x256 block tile, 512 threads = 8 waves of 64x64
// (2x LDS arithmetic intensity vs 64x32: LDS-read was the measured limiter),
// tri-buffered LDS (144 KB) with depth-2 prefetch, ONE barrier + counted
// vmcnt(6) per K-step (tile t+2's 6 loads/thread stay in flight).
// ---------------------------------------------------------------------------
template<int WRITE_KB>
__global__ __launch_bounds__(512)
void gemm_qkv(const unsigned short* __restrict__ xb, const unsigned short* __restrict__ wtb,
              unsigned short* __restrict__ qb, float* __restrict__ kout,
              float* __restrict__ vout, unsigned short* __restrict__ kb,
              unsigned short* __restrict__ vtt)
{
    __shared__ unsigned short As[3][128 * 64];   // 3 x 16 KB
    __shared__ unsigned short Bs[3][256 * 64];   // 3 x 32 KB

    const int tid = threadIdx.x;
    const int which = blockIdx.x >> 2;             // 0=q 1=k 2=v
    const int n0 = (blockIdx.x & 3) * 256;
    const int m0 = blockIdx.y * 128;
    const unsigned short* wt = wtb + (size_t)which * C_ * C_;

    const int lane = tid & 63, w = tid >> 6;       // w: 0..7
    const int wm = (w >> 2) * 64, wn = (w & 3) * 64;
    const int fr = lane & 15, qd = lane >> 4;

    // staging addresses. A: 1024 chunks (2/thread). B: 2048 chunks (4/thread).
    int arow[2], aofs[2]; size_t alds[2];
#pragma unroll
    for (int cc = 0; cc < 2; ++cc) {
        const int c = tid + cc * 512;
        arow[cc] = c >> 3;
        aofs[cc] = ((c & 7) ^ (arow[cc] & 7)) * 8;
        alds[cc] = (size_t)c * 16;
    }
    int brow[4], bofs[4]; size_t blds[4];
#pragma unroll
    for (int cc = 0; cc < 4; ++cc) {
        const int c = tid + cc * 512;
        brow[cc] = c >> 3;
        bofs[cc] = ((c & 7) ^ (brow[cc] & 7)) * 8;
        blds[cc] = (size_t)c * 16;
    }

#define STAGE(s, kt)                                                                   \
    {                                                                                  \
        _Pragma("unroll")                                                              \
        for (int cc = 0; cc < 2; ++cc)                                                 \
            __builtin_amdgcn_global_load_lds(                                          \
                (gaddr_t*)(xb + (size_t)(m0 + arow[cc]) * C_ + (kt) * 64 + aofs[cc]),  \
                (laddr_t*)((char*)As[s] + alds[cc]), 16, 0, 0);                        \
        _Pragma("unroll")                                                              \
        for (int cc = 0; cc < 4; ++cc)                                                 \
            __builtin_amdgcn_global_load_lds(                                          \
                (gaddr_t*)(wt + (size_t)(n0 + brow[cc]) * C_ + (kt) * 64 + bofs[cc]),  \
                (laddr_t*)((char*)Bs[s] + blds[cc]), 16, 0, 0);                        \
    }

    f32x4 acc[4][4] = {};
    constexpr int NT = C_ / 64;                    // 16 K-tiles

    STAGE(0, 0);
    STAGE(1, 1);
    asm volatile("s_waitcnt vmcnt(6)" ::: "memory");   // tile0 landed; tile1 in flight
    __builtin_amdgcn_s_barrier();
    __builtin_amdgcn_sched_barrier(0);

    for (int t = 0; t < NT; ++t) {
        const int s = t % 3;
        if (t + 2 < NT) STAGE((t + 2) % 3, t + 2);     // slot freed at end of iter t-1

        const unsigned short* Ac = As[s];
        const unsigned short* Bc = Bs[s];
#pragma unroll
        for (int half = 0; half < 2; ++half) {
            bf16x8 af[4], bfv[4];
#pragma unroll
            for (int mt = 0; mt < 4; ++mt) {
                const int row = wm + mt * 16 + fr, dg = half * 4 + qd;
                af[mt] = *(const bf16x8*)&Ac[row * 64 + ((dg ^ (row & 7)) * 8)];
            }
#pragma unroll
            for (int nt = 0; nt < 4; ++nt) {
                const int row = wn + nt * 16 + fr, dg = half * 4 + qd;
                bfv[nt] = *(const bf16x8*)&Bc[row * 64 + ((dg ^ (row & 7)) * 8)];
            }
#pragma unroll
            for (int mt = 0; mt < 4; ++mt)
#pragma unroll
                for (int nt = 0; nt < 4; ++nt)
                    acc[mt][nt] = __builtin_amdgcn_mfma_f32_16x16x32_bf16(
                        bfv[nt], af[mt], acc[mt][nt], 0, 0, 0);
        }

        // wait tile t+1 (issued a full iteration ago); keep t+2's 6 in flight
        if (t + 2 < NT)      asm volatile("s_waitcnt vmcnt(6)" ::: "memory");
        else if (t + 1 < NT) asm volatile("s_waitcnt vmcnt(0)" ::: "memory");
        __builtin_amdgcn_s_barrier();
        __builtin_amdgcn_sched_barrier(0);
    }
#undef STAGE

    // Flipped C/D layout: col(lane&15)=m token, row=(lane>>4)*4+reg = n feature
#pragma unroll
    for (int mt = 0; mt < 4; ++mt) {
        const int mm = m0 + wm + mt * 16 + fr;
        const int b = mm >> 11, t = mm & (T_ - 1);
#pragma unroll
        for (int nt = 0; nt < 4; ++nt) {
            const int nn = n0 + wn + nt * 16 + qd * 4;
            const int h = nn >> 6, d0 = nn & 63;
            const int bh = b * H_ + h;
            const size_t off = ((size_t)bh * T_ + t) * D_ + d0;
            const f32x4 a4 = acc[mt][nt];
            if (which == 0) {
                *(ushort4*)(qb + off) =
                    make_ushort4(f2bf(a4[0]), f2bf(a4[1]), f2bf(a4[2]), f2bf(a4[3]));
            } else if (which == 1) {
                *(float4*)(kout + off) = make_float4(a4[0], a4[1], a4[2], a4[3]);
                if (WRITE_KB)
                    *(ushort4*)(kb + off) =
                        make_ushort4(f2bf(a4[0]), f2bf(a4[1]), f2bf(a4[2]), f2bf(a4[3]));
            } else {
                *(float4*)(vout + off) = make_float4(a4[0], a4[1], a4[2], a4[3]);
                // fused V^T: vtt[bh][t>>6][d][t&63]
                unsigned short* vb = vtt
                    + (((size_t)bh * (T_ / 64) + (t >> 6)) * 64 + d0) * 64 + (t & 63);
#pragma unroll
                for (int r = 0; r < 4; ++r) vb[(size_t)r * 64] = f2bf(a4[r]);
            }
        }
    }
}

// ---------------------------------------------------------------------------
// Output projection v2 — tri-buffer depth-2, 128x128, 512 threads (R6 config).
// ---------------------------------------------------------------------------
__global__ __launch_bounds__(512)
void gemm_o(const unsigned short* __restrict__ ab, const unsigned short* __restrict__ wot,
            const float* __restrict__ bo, float* __restrict__ out)
{
    __shared__ unsigned short As[3][128 * 64];
    __shared__ unsigned short Bs[3][128 * 64];

    const int tid = threadIdx.x;
    const int n0 = blockIdx.x * 128;
    const int m0 = blockIdx.y * 128;

    const int lane = tid & 63, w = tid >> 6;
    const int wm = (w >> 2) * 64, wn2 = (w & 3) * 32;
    const int fr = lane & 15, qd = lane >> 4;

    int crow[2], cofs[2]; size_t clds[2];
#pragma unroll
    for (int cc = 0; cc < 2; ++cc) {
        const int c = tid + cc * 512;
        crow[cc] = c >> 3;
        cofs[cc] = ((c & 7) ^ (crow[cc] & 7)) * 8;
        clds[cc] = (size_t)c * 16;
    }

#define STAGE_O(s, kt)                                                             \
    {                                                                              \
        _Pragma("unroll")                                                          \
        for (int cc = 0; cc < 2; ++cc) {                                           \
            __builtin_amdgcn_global_load_lds(                                      \
                (gaddr_t*)(ab + (size_t)(m0 + crow[cc]) * C_ + (kt) * 64 + cofs[cc]),  \
                (laddr_t*)((char*)As[s] + clds[cc]), 16, 0, 0);                    \
            __builtin_amdgcn_global_load_lds(                                      \
                (gaddr_t*)(wot + (size_t)(n0 + crow[cc]) * C_ + (kt) * 64 + cofs[cc]), \
                (laddr_t*)((char*)Bs[s] + clds[cc]), 16, 0, 0);                    \
        }                                                                          \
    }

    f32x4 acc[4][2] = {};
    constexpr int NT = C_ / 64;

    STAGE_O(0, 0);
    STAGE_O(1, 1);
    asm volatile("s_waitcnt vmcnt(4)" ::: "memory");
    __builtin_amdgcn_s_barrier();
    __builtin_amdgcn_sched_barrier(0);

    for (int t = 0; t < NT; ++t) {
        const int s = t % 3;
        if (t + 2 < NT) STAGE_O((t + 2) % 3, t + 2);

        const unsigned short* Ac = As[s];
        const unsigned short* Bc = Bs[s];
#pragma unroll
        for (int half = 0; half < 2; ++half) {
            bf16x8 af[4], bfv[2];
#pragma unroll
            for (int mt = 0; mt < 4; ++mt) {
                const int row = wm + mt * 16 + fr, dg = half * 4 + qd;
                af[mt] = *(const bf16x8*)&Ac[row * 64 + ((dg ^ (row & 7)) * 8)];
            }
#pragma unroll
            for (int nt = 0; nt < 2; ++nt) {
                const int row = wn2 + nt * 16 + fr, dg = half * 4 + qd;
                bfv[nt] = *(const bf16x8*)&Bc[row * 64 + ((dg ^ (row & 7)) * 8)];
            }
#pragma unroll
            for (int mt = 0; mt < 4; ++mt)
#pragma unroll
                for (int nt = 0; nt < 2; ++nt)
                    acc[mt][nt] = __builtin_amdgcn_mfma_f32_16x16x32_bf16(
                        bfv[nt], af[mt], acc[mt][nt], 0, 0, 0);
        }

        if (t + 2 < NT)      asm volatile("s_waitcnt vmcnt(4)" ::: "memory");
        else if (t + 1 < NT) asm volatile("s_waitcnt vmcnt(0)" ::: "memory");
        __builtin_amdgcn_s_barrier();
        __builtin_amdgcn_sched_barrier(0);
    }
#undef STAGE_O

#pragma unroll
    for (int mt = 0; mt < 4; ++mt) {
        const int mm = m0 + wm + mt * 16 + fr;
#pragma unroll
        for (int nt = 0; nt < 2; ++nt) {
            const int nn = n0 + wn2 + nt * 16 + qd * 4;
            const float4 b4 = *(const float4*)(bo + nn);
            *(float4*)(out + (size_t)mm * C_ + nn) =
                make_float4(acc[mt][nt][0] + b4.x, acc[mt][nt][1] + b4.y,
                            acc[mt][nt][2] + b4.z, acc[mt][nt][3] + b4.w);
        }
    }
}

// ---------------------------------------------------------------------------
// MFMA flash attention v6 — 64-row Q-tiles, double-buffered K/V (R4 config).
// ---------------------------------------------------------------------------
__global__ __launch_bounds__(256)
void attn_lds(const unsigned short* __restrict__ qb, const unsigned short* __restrict__ kb,
              const unsigned short* __restrict__ vtt, unsigned short* __restrict__ attb)
{
    __shared__ unsigned short Ks[2][64 * 64];
    __shared__ unsigned short Vs[2][64 * 64];
    __shared__ alignas(16) unsigned short Pt[4][16 * 72];

    const int tid = threadIdx.x;
    const int lane = tid & 63, w = tid >> 6;
    const int fr = lane & 15, qd = lane >> 4;

    const int blk = blockIdx.x;
    const int xcd = blk & 7, within = blk >> 3;      // within: 0..127
    const int bh = xcd * 4 + (within & 3);
    const int jj = within >> 2;                      // 0..31
    const int kk_ = jj >> 3, ii_ = jj & 7;
    const int qt = (kk_ == 0) ? (31 - ii_) : (kk_ == 1) ? ii_
                 : (kk_ == 2) ? (23 - ii_) : (8 + ii_);
    const int b = bh >> 4, h = bh & 15;

    unsigned short* Pw = Pt[w];
    const unsigned short* qB = qb  + (size_t)bh * T_ * D_;
    const unsigned short* kB = kb  + (size_t)bh * T_ * D_;
    const unsigned short* vT = vtt + (size_t)bh * (T_ / 64) * 64 * 64;

    const int qr0 = qt * 64 + w * 16;
    const int qrow_g = qr0 + fr;

    bf16x8 aq0 = *(const bf16x8*)(qB + (size_t)(qr0 + fr) * D_ + qd * 8);
    bf16x8 aq1 = *(const bf16x8*)(qB + (size_t)(qr0 + fr) * D_ + 32 + qd * 8);

    f32x4 accT[4] = {};
    float l_i = 0.0f;
    const float sc2 = 0.18033688f;                   // log2(e) / sqrt(64)

    const int L0 = w * 128 + lane, L1 = L0 + 64;
    const int r0 = L0 >> 3, e0 = (((L0 & 7) ^ (r0 & 7)) * 8);
    const int r1 = L1 >> 3, e1 = (((L1 & 7) ^ (r1 & 7)) * 8);

    // prologue: stage tile 0 into buffer 0
    {
        __builtin_amdgcn_global_load_lds((gaddr_t*)(kB + r0 * 64 + e0),
            (laddr_t*)((char*)Ks[0] + (size_t)L0 * 16), 16, 0, 0);
        __builtin_amdgcn_global_load_lds((gaddr_t*)(kB + r1 * 64 + e1),
            (laddr_t*)((char*)Ks[0] + (size_t)L1 * 16), 16, 0, 0);
        __builtin_amdgcn_global_load_lds((gaddr_t*)(vT + r0 * 64 + e0),
            (laddr_t*)((char*)Vs[0] + (size_t)L0 * 16), 16, 0, 0);
        __builtin_amdgcn_global_load_lds((gaddr_t*)(vT + r1 * 64 + e1),
            (laddr_t*)((char*)Vs[0] + (size_t)L1 * 16), 16, 0, 0);
    }
    asm volatile("s_waitcnt vmcnt(0)" ::: "memory");
    __builtin_amdgcn_s_barrier();
    __builtin_amdgcn_sched_barrier(0);

    for (int jt = 0; jt <= qt; ++jt) {
        const int cur = jt & 1;
        if (jt < qt) {                                // prefetch jt+1
            const unsigned short* kt = kB + (size_t)((jt + 1) * 64) * 64;
            const unsigned short* vt = vT + (size_t)(jt + 1) * 4096;
            char* Kn = (char*)Ks[cur ^ 1];
            char* Vn = (char*)Vs[cur ^ 1];
            __builtin_amdgcn_global_load_lds((gaddr_t*)(kt + r0 * 64 + e0),
                (laddr_t*)(Kn + (size_t)L0 * 16), 16, 0, 0);
            __builtin_amdgcn_global_load_lds((gaddr_t*)(kt + r1 * 64 + e1),
                (laddr_t*)(Kn + (size_t)L1 * 16), 16, 0, 0);
            __builtin_amdgcn_global_load_lds((gaddr_t*)(vt + r0 * 64 + e0),
                (laddr_t*)(Vn + (size_t)L0 * 16), 16, 0, 0);
            __builtin_amdgcn_global_load_lds((gaddr_t*)(vt + r1 * 64 + e1),
                (laddr_t*)(Vn + (size_t)L1 * 16), 16, 0, 0);
        }
        const unsigned short* Kc = Ks[cur];
        const unsigned short* Vc = Vs[cur];

        bf16x8 bk[8];
#pragma unroll
        for (int q8 = 0; q8 < 8; ++q8) {
            const int row = (q8 >> 1) * 16 + fr;
            const int dg = (q8 & 1) * 4 + qd;
            bk[q8] = *(const bf16x8*)&Kc[row * 64 + ((dg ^ (row & 7)) * 8)];
        }

        f32x4 s4[4] = {};
        __builtin_amdgcn_s_setprio(1);
#pragma unroll
        for (int nt = 0; nt < 4; ++nt) {
            s4[nt] = __builtin_amdgcn_mfma_f32_16x16x32_bf16(bk[nt * 2 + 0], aq0, s4[nt], 0, 0, 0);
            s4[nt] = __builtin_amdgcn_mfma_f32_16x16x32_bf16(bk[nt * 2 + 1], aq1, s4[nt], 0, 0, 0);
        }
        __builtin_amdgcn_s_setprio(0);

        if (jt == qt) {
            const int kbase = jt * 64 + qd * 4;
#pragma unroll
            for (int nt = 0; nt < 4; ++nt)
#pragma unroll
            for (int r = 0; r < 4; ++r) {
                const int kcol = kbase + nt * 16 + r;
                const float pv = (kcol <= qrow_g)
                               ? __builtin_amdgcn_exp2f(s4[nt][r] * sc2) : 0.0f;
                s4[nt][r] = pv;
                l_i += pv;
            }
        } else {
#pragma unroll
            for (int nt = 0; nt < 4; ++nt)
#pragma unroll
            for (int r = 0; r < 4; ++r) {
                const float pv = __builtin_amdgcn_exp2f(s4[nt][r] * sc2);
                s4[nt][r] = pv;
                l_i += pv;
            }
        }

#pragma unroll
        for (int nt = 0; nt < 4; ++nt) {
            union { __hip_bfloat162 h2[2]; unsigned long long u; } pk;
            pk.h2[0] = __float22bfloat162_rn(make_float2(s4[nt][0], s4[nt][1]));
            pk.h2[1] = __float22bfloat162_rn(make_float2(s4[nt][2], s4[nt][3]));
            *(unsigned long long*)&Pw[fr * 72 + nt * 16 + qd * 4] = pk.u;
        }
        const bf16x8 ap0 = *(const bf16x8*)&Pw[fr * 72 + qd * 8];
        const bf16x8 ap1 = *(const bf16x8*)&Pw[fr * 72 + 32 + qd * 8];

        bf16x8 bv[8];
#pragma unroll
        for (int q8 = 0; q8 < 8; ++q8) {
            const int row = (q8 >> 1) * 16 + fr;
            const int dg = (q8 & 1) * 4 + qd;
            bv[q8] = *(const bf16x8*)&Vc[row * 64 + ((dg ^ (row & 7)) * 8)];
        }

        __builtin_amdgcn_s_setprio(1);
#pragma unroll
        for (int nt = 0; nt < 4; ++nt) {
            accT[nt] = __builtin_amdgcn_mfma_f32_16x16x32_bf16(bv[nt * 2 + 0], ap0, accT[nt], 0, 0, 0);
            accT[nt] = __builtin_amdgcn_mfma_f32_16x16x32_bf16(bv[nt * 2 + 1], ap1, accT[nt], 0, 0, 0);
        }
        __builtin_amdgcn_s_setprio(0);

        // next tile's loads have had the whole body to land
        asm volatile("s_waitcnt vmcnt(0)" ::: "memory");
        __builtin_amdgcn_s_barrier();
        __builtin_amdgcn_sched_barrier(0);
    }

    l_i += __shfl_xor(l_i, 16);
    l_i += __shfl_xor(l_i, 32);
    const float inv = 1.0f / l_i;

#pragma unroll
    for (int nt = 0; nt < 4; ++nt) {
        union { __hip_bfloat162 h2[2]; unsigned long long u; } ok;
        ok.h2[0] = __float22bfloat162_rn(make_float2(accT[nt][0] * inv, accT[nt][1] * inv));
        ok.h2[1] = __float22bfloat162_rn(make_float2(accT[nt][2] * inv, accT[nt][3] * inv));
        *(unsigned long long*)&Pw[fr * 72 + nt * 16 + qd * 4] = ok.u;
    }
    {
        const int row = lane >> 2, d0 = (lane & 3) * 16;
        const bf16x8 o0 = *(const bf16x8*)&Pw[row * 72 + d0];
        const bf16x8 o1 = *(const bf16x8*)&Pw[row * 72 + d0 + 8];
        unsigned short* op = attb + ((size_t)b * T_ + qr0 + row) * C_ + h * 64 + d0;
        *(bf16x8*)op = o0;
        *(bf16x8*)(op + 8) = o1;
    }
}

// ---------------------------------------------------------------------------
// Fallback (ws too small for kb): per-wave kernel, fp32 K + tiled V^T.
// ---------------------------------------------------------------------------
__global__ __launch_bounds__(256)
void attn_v4(const unsigned short* __restrict__ qb, const float* __restrict__ kf,
             const unsigned short* __restrict__ vtt, unsigned short* __restrict__ attb)
{
    __shared__ alignas(16) unsigned short Pt[4][16 * 72];

    const int tid = threadIdx.x;
    const int lane = tid & 63, w = tid >> 6;
    const int fr = lane & 15, qd = lane >> 4;

    const int blk = blockIdx.x;
    const int xcd = blk & 7, within = blk >> 3;
    const int bh = xcd * 4 + (within & 3);
    const int jj = within >> 2;
    const int kk_ = jj >> 3, ii_ = jj & 7;
    const int qt = (kk_ == 0) ? (31 - ii_) : (kk_ == 1) ? ii_
                 : (kk_ == 2) ? (23 - ii_) : (8 + ii_);
    const int b = bh >> 4, h = bh & 15;

    unsigned short* Pw = Pt[w];
    const unsigned short* qB = qb  + (size_t)bh * T_ * D_;
    const float*          kB = kf  + (size_t)bh * T_ * D_;
    const unsigned short* vT = vtt + (size_t)bh * (T_ / 64) * 64 * 64;

    const int qr0 = qt * 64 + w * 16;
    const int qrow_g = qr0 + fr;

    bf16x8 aq0 = *(const bf16x8*)(qB + (size_t)(qr0 + fr) * D_ + qd * 8);
    bf16x8 aq1 = *(const bf16x8*)(qB + (size_t)(qr0 + fr) * D_ + 32 + qd * 8);

    f32x4 accT[4] = {};
    float l_i = 0.0f;
    const float sc2 = 0.18033688f;

    for (int jt = 0; jt <= qt; ++jt) {
        bf16x8 bk[8];
#pragma unroll
        for (int q8 = 0; q8 < 8; ++q8) {
            const float* p = kB + (size_t)(jt * 64 + (q8 >> 1) * 16 + fr) * D_
                           + (q8 & 1) * 32 + qd * 8;
            bk[q8] = cvt8(*(const float4*)p, *(const float4*)(p + 4));
        }
        f32x4 s4[4] = {};
#pragma unroll
        for (int nt = 0; nt < 4; ++nt) {
            s4[nt] = __builtin_amdgcn_mfma_f32_16x16x32_bf16(bk[nt * 2 + 0], aq0, s4[nt], 0, 0, 0);
            s4[nt] = __builtin_amdgcn_mfma_f32_16x16x32_bf16(bk[nt * 2 + 1], aq1, s4[nt], 0, 0, 0);
        }
        if (jt == qt) {
            const int kbase = jt * 64 + qd * 4;
#pragma unroll
            for (int nt = 0; nt < 4; ++nt)
#pragma unroll
            for (int r = 0; r < 4; ++r) {
                const int kcol = kbase + nt * 16 + r;
                const float pv = (kcol <= qrow_g)
                               ? __builtin_amdgcn_exp2f(s4[nt][r] * sc2) : 0.0f;
                s4[nt][r] = pv; l_i += pv;
            }
        } else {
#pragma unroll
            for (int nt = 0; nt < 4; ++nt)
#pragma unroll
            for (int r = 0; r < 4; ++r) {
                const float pv = __builtin_amdgcn_exp2f(s4[nt][r] * sc2);
                s4[nt][r] = pv; l_i += pv;
            }
        }
#pragma unroll
        for (int nt = 0; nt < 4; ++nt) {
            union { __hip_bfloat162 h2[2]; unsigned long long u; } pk;
            pk.h2[0] = __float22bfloat162_rn(make_float2(s4[nt][0], s4[nt][1]));
            pk.h2[1] = __float22bfloat162_rn(make_float2(s4[nt][2], s4[nt][3]));
            *(unsigned long long*)&Pw[fr * 72 + nt * 16 + qd * 4] = pk.u;
        }
        const bf16x8 ap0 = *(const bf16x8*)&Pw[fr * 72 + qd * 8];
        const bf16x8 ap1 = *(const bf16x8*)&Pw[fr * 72 + 32 + qd * 8];

        bf16x8 bv[8];
#pragma unroll
        for (int q8 = 0; q8 < 8; ++q8)
            bv[q8] = *(const bf16x8*)(vT + (size_t)jt * 4096
                                      + ((q8 >> 1) * 16 + fr) * 64 + (q8 & 1) * 32 + qd * 8);
#pragma unroll
        for (int nt = 0; nt < 4; ++nt) {
            accT[nt] = __builtin_amdgcn_mfma_f32_16x16x32_bf16(bv[nt * 2 + 0], ap0, accT[nt], 0, 0, 0);
            accT[nt] = __builtin_amdgcn_mfma_f32_16x16x32_bf16(bv[nt * 2 + 1], ap1, accT[nt], 0, 0, 0);
        }
    }

    l_i += __shfl_xor(l_i, 16);
    l_i += __shfl_xor(l_i, 32);
    const float inv = 1.0f / l_i;
#pragma unroll
    for (int nt = 0; nt < 4; ++nt) {
        union { __hip_bfloat162 h2[2]; unsigned long long u; } ok;
        ok.h2[0] = __float22bfloat162_rn(make_float2(accT[nt][0] * inv, accT[nt][1] * inv));
        ok.h2[1] = __float22bfloat162_rn(make_float2(accT[nt][2] * inv, accT[nt][3] * inv));
        *(unsigned long long*)&Pw[fr * 72 + nt * 16 + qd * 4] = ok.u;
    }
    {
        const int row = lane >> 2, d0 = (lane & 3) * 16;
        const bf16x8 o0 = *(const bf16x8*)&Pw[row * 72 + d0];
        const bf16x8 o1 = *(const bf16x8*)&Pw[row * 72 + d0 + 8];
        unsigned short* op = attb + ((size_t)b * T_ + qr0 + row) * C_ + h * 64 + d0;
        *(bf16x8*)op = o0;
        *(bf16x8*)(op + 8) = o1;
    }
}

// ---------------------------------------------------------------------------
extern "C" void kernel_launch(void* const* d_in, const int* in_sizes, int n_in,
                              void* d_out, int out_size, void* d_ws, size_t ws_size,
                              hipStream_t stream)
{
    (void)in_sizes; (void)n_in; (void)out_size;
    const float* x  = (const float*)d_in[0];
    const float* Wq = (const float*)d_in[1];
    const float* Wk = (const float*)d_in[2];
    const float* Wv = (const float*)d_in[3];
    const float* Wo = (const float*)d_in[4];
    const float* bo = (const float*)d_in[5];

    float* out  = (float*)d_out;                       // (B,T,C)
    float* kout = out  + (size_t)M_ * C_;              // (B,H,T,D) fp32
    float* vout = kout + (size_t)B_ * H_ * T_ * D_;    // (B,H,T,D) fp32

    // ws: xb(8M) | wtb(8M) | qb(8M) | vtt(8M) | kb(8M, optional); attb aliases xb
    unsigned short* xb   = (unsigned short*)d_ws;
    unsigned short* wtb  = xb  + (size_t)M_ * C_;
    unsigned short* qb   = wtb + (size_t)4 * C_ * C_;
    unsigned short* vtt  = qb  + (size_t)M_ * C_;
    unsigned short* kb   = vtt + (size_t)M_ * C_;
    unsigned short* attb = xb;
    const bool use_kb = ws_size >= (size_t)40 * 1024 * 1024;

    prep<<<dim3(16, 16, 5), 256, 0, stream>>>(x, Wq, Wk, Wv, Wo, xb, wtb);

    if (use_kb)
        gemm_qkv<1><<<dim3(12, 32), 512, 0, stream>>>(xb, wtb, qb, kout, vout, kb, vtt);
    else
        gemm_qkv<0><<<dim3(12, 32), 512, 0, stream>>>(xb, wtb, qb, kout, vout, kb, vtt);

    if (use_kb)
        attn_lds<<<1024, 256, 0, stream>>>(qb, kb, vtt, attb);
    else
        attn_v4<<<1024, 256, 0, stream>>>(qb, kout, vtt, attb);

    gemm_o<<<dim3(8, 32), 512, 0, stream>>>(attb, wtb + (size_t)3 * C_ * C_, bo, out);
}

// Round 8
// 189.134 us; speedup vs baseline: 1.0547x; 1.0547x over previous
//
#include <hip/hip_runtime.h>
#include <hip/hip_bf16.h>

constexpr int B_ = 2;
constexpr int T_ = 2048;
constexpr int C_ = 1024;
constexpr int H_ = 16;
constexpr int D_ = 64;
constexpr int M_ = B_ * T_;   // 4096 rows

typedef __attribute__((ext_vector_type(8))) short bf16x8;   // 8 bf16 = 4 VGPRs
typedef __attribute__((ext_vector_type(4))) float f32x4;
typedef const __attribute__((address_space(1))) void gaddr_t;
typedef __attribute__((address_space(3))) void laddr_t;

__device__ __forceinline__ unsigned short f2bf(float f) {   // fp32 -> bf16 RNE
    unsigned u = __float_as_uint(f);
    return (unsigned short)((u + 0x7fffu + ((u >> 16) & 1u)) >> 16);
}

union BF8 { bf16x8 v; __hip_bfloat162 h[4]; };

__device__ __forceinline__ bf16x8 cvt8(const float4 a, const float4 b) {
    BF8 r;
    r.h[0] = __float22bfloat162_rn(make_float2(a.x, a.y));
    r.h[1] = __float22bfloat162_rn(make_float2(a.z, a.w));
    r.h[2] = __float22bfloat162_rn(make_float2(b.x, b.y));
    r.h[3] = __float22bfloat162_rn(make_float2(b.z, b.w));
    return r.v;
}

// ---------------------------------------------------------------------------
// prep: z<4 -> W (K x N fp32) -> Wt (N x K bf16); z==4 -> x fp32 -> xb bf16.
// ---------------------------------------------------------------------------
__global__ __launch_bounds__(256)
void prep(const float* __restrict__ x, const float* __restrict__ Wq,
          const float* __restrict__ Wk, const float* __restrict__ Wv,
          const float* __restrict__ Wo, unsigned short* __restrict__ xb,
          unsigned short* __restrict__ wtb)
{
    const int z = blockIdx.z;
    const int tid = threadIdx.x;

    if (z == 4) {                                   // x cast: 256 blocks handle 1M float4
        const int base = (blockIdx.y * 16 + blockIdx.x) * 4096 + tid;
#pragma unroll
        for (int i = 0; i < 16; ++i) {
            const int idx = base + i * 256;
            float4 v = ((const float4*)x)[idx];
            union { __hip_bfloat162 h[2]; ushort4 u; } o;
            o.h[0] = __float22bfloat162_rn(make_float2(v.x, v.y));
            o.h[1] = __float22bfloat162_rn(make_float2(v.z, v.w));
            ((ushort4*)xb)[idx] = o.u;
        }
        return;
    }

    __shared__ float tile[64][65];
    const float* W = (z == 0) ? Wq : (z == 1) ? Wk : (z == 2) ? Wv : Wo;
    unsigned short* O = wtb + (size_t)z * C_ * C_;

    const int n0 = blockIdx.x * 64, k0 = blockIdx.y * 64;
    const int r = tid >> 4, c4 = (tid & 15) * 4;

#pragma unroll
    for (int i = 0; i < 4; ++i) {
        const int kk = i * 16 + r;
        float4 v = *(const float4*)(W + (size_t)(k0 + kk) * C_ + n0 + c4);
        tile[c4 + 0][kk] = v.x;
        tile[c4 + 1][kk] = v.y;
        tile[c4 + 2][kk] = v.z;
        tile[c4 + 3][kk] = v.w;
    }
    __syncthreads();
#pragma unroll
    for (int i = 0; i < 4; ++i) {
        const int nn = i * 16 + r;
        ushort4 o;
        o.x = f2bf(tile[nn][c4 + 0]);
        o.y = f2bf(tile[nn][c4 + 1]);
        o.z = f2bf(tile[nn][c4 + 2]);
        o.w = f2bf(tile[nn][c4 + 3]);
        *(ushort4*)(O + (size_t)(n0 + nn) * C_ + k0 + c4) = o;
    }
}

// ---------------------------------------------------------------------------
// Fused QKV GEMM — R6-EXACT best measured (48.9 us): 128x128 tile, 512 thr
// (8 waves of 64x32), tri-buffered LDS (96 KB, 2 blocks/CU) with depth-2
// prefetch, ONE barrier + counted vmcnt(4) per K-step.
// ---------------------------------------------------------------------------
template<int WRITE_KB>
__global__ __launch_bounds__(512)
void gemm_qkv(const unsigned short* __restrict__ xb, const unsigned short* __restrict__ wtb,
              unsigned short* __restrict__ qb, float* __restrict__ kout,
              float* __restrict__ vout, unsigned short* __restrict__ kb,
              unsigned short* __restrict__ vtt)
{
    __shared__ unsigned short As[3][128 * 64];   // 3 x 16 KB
    __shared__ unsigned short Bs[3][128 * 64];   // 3 x 16 KB

    const int tid = threadIdx.x;
    const int which = blockIdx.x >> 3;             // 0=q 1=k 2=v
    const int n0 = (blockIdx.x & 7) * 128;
    const int m0 = blockIdx.y * 128;
    const unsigned short* wt = wtb + (size_t)which * C_ * C_;

    const int lane = tid & 63, w = tid >> 6;       // w: 0..7
    const int wm = (w >> 2) * 64, wn2 = (w & 3) * 32;
    const int fr = lane & 15, qd = lane >> 4;

    int crow[2], cofs[2]; size_t clds[2];
#pragma unroll
    for (int cc = 0; cc < 2; ++cc) {
        const int c = tid + cc * 512;
        crow[cc] = c >> 3;
        cofs[cc] = ((c & 7) ^ (crow[cc] & 7)) * 8;
        clds[cc] = (size_t)c * 16;
    }

#define STAGE(s, kt)                                                               \
    {                                                                              \
        _Pragma("unroll")                                                          \
        for (int cc = 0; cc < 2; ++cc) {                                           \
            __builtin_amdgcn_global_load_lds(                                      \
                (gaddr_t*)(xb + (size_t)(m0 + crow[cc]) * C_ + (kt) * 64 + cofs[cc]), \
                (laddr_t*)((char*)As[s] + clds[cc]), 16, 0, 0);                    \
            __builtin_amdgcn_global_load_lds(                                      \
                (gaddr_t*)(wt + (size_t)(n0 + crow[cc]) * C_ + (kt) * 64 + cofs[cc]), \
                (laddr_t*)((char*)Bs[s] + clds[cc]), 16, 0, 0);                    \
        }                                                                          \
    }

    f32x4 acc[4][2] = {};
    constexpr int NT = C_ / 64;                    // 16 K-tiles

    STAGE(0, 0);
    STAGE(1, 1);
    asm volatile("s_waitcnt vmcnt(4)" ::: "memory");   // tile0 landed; tile1 in flight
    __builtin_amdgcn_s_barrier();
    __builtin_amdgcn_sched_barrier(0);

    for (int t = 0; t < NT; ++t) {
        const int s = t % 3;
        if (t + 2 < NT) STAGE((t + 2) % 3, t + 2);     // slot freed at end of iter t-1

        const unsigned short* Ac = As[s];
        const unsigned short* Bc = Bs[s];
#pragma unroll
        for (int half = 0; half < 2; ++half) {
            bf16x8 af[4], bfv[2];
#pragma unroll
            for (int mt = 0; mt < 4; ++mt) {
                const int row = wm + mt * 16 + fr, dg = half * 4 + qd;
                af[mt] = *(const bf16x8*)&Ac[row * 64 + ((dg ^ (row & 7)) * 8)];
            }
#pragma unroll
            for (int nt = 0; nt < 2; ++nt) {
                const int row = wn2 + nt * 16 + fr, dg = half * 4 + qd;
                bfv[nt] = *(const bf16x8*)&Bc[row * 64 + ((dg ^ (row & 7)) * 8)];
            }
#pragma unroll
            for (int mt = 0; mt < 4; ++mt)
#pragma unroll
                for (int nt = 0; nt < 2; ++nt)
                    acc[mt][nt] = __builtin_amdgcn_mfma_f32_16x16x32_bf16(
                        bfv[nt], af[mt], acc[mt][nt], 0, 0, 0);
        }

        // wait tile t+1 (issued a full iteration ago); keep t+2 in flight
        if (t + 2 < NT)      asm volatile("s_waitcnt vmcnt(4)" ::: "memory");
        else if (t + 1 < NT) asm volatile("s_waitcnt vmcnt(0)" ::: "memory");
        __builtin_amdgcn_s_barrier();
        __builtin_amdgcn_sched_barrier(0);
    }
#undef STAGE

    // Flipped C/D layout: col(lane&15)=m token, row=(lane>>4)*4+reg = n feature
#pragma unroll
    for (int mt = 0; mt < 4; ++mt) {
        const int mm = m0 + wm + mt * 16 + fr;
        const int b = mm >> 11, t = mm & (T_ - 1);
#pragma unroll
        for (int nt = 0; nt < 2; ++nt) {
            const int nn = n0 + wn2 + nt * 16 + qd * 4;
            const int h = nn >> 6, d0 = nn & 63;
            const int bh = b * H_ + h;
            const size_t off = ((size_t)bh * T_ + t) * D_ + d0;
            const f32x4 a4 = acc[mt][nt];
            if (which == 0) {
                *(ushort4*)(qb + off) =
                    make_ushort4(f2bf(a4[0]), f2bf(a4[1]), f2bf(a4[2]), f2bf(a4[3]));
            } else if (which == 1) {
                *(float4*)(kout + off) = make_float4(a4[0], a4[1], a4[2], a4[3]);
                if (WRITE_KB)
                    *(ushort4*)(kb + off) =
                        make_ushort4(f2bf(a4[0]), f2bf(a4[1]), f2bf(a4[2]), f2bf(a4[3]));
            } else {
                *(float4*)(vout + off) = make_float4(a4[0], a4[1], a4[2], a4[3]);
                // fused V^T: vtt[bh][t>>6][d][t&63]
                unsigned short* vb = vtt
                    + (((size_t)bh * (T_ / 64) + (t >> 6)) * 64 + d0) * 64 + (t & 63);
#pragma unroll
                for (int r = 0; r < 4; ++r) vb[(size_t)r * 64] = f2bf(a4[r]);
            }
        }
    }
}

// ---------------------------------------------------------------------------
// Output projection — tri-buffer depth-2, 128x128, 512 threads (R6 config).
// ---------------------------------------------------------------------------
__global__ __launch_bounds__(512)
void gemm_o(const unsigned short* __restrict__ ab, const unsigned short* __restrict__ wot,
            const float* __restrict__ bo, float* __restrict__ out)
{
    __shared__ unsigned short As[3][128 * 64];
    __shared__ unsigned short Bs[3][128 * 64];

    const int tid = threadIdx.x;
    const int n0 = blockIdx.x * 128;
    const int m0 = blockIdx.y * 128;

    const int lane = tid & 63, w = tid >> 6;
    const int wm = (w >> 2) * 64, wn2 = (w & 3) * 32;
    const int fr = lane & 15, qd = lane >> 4;

    int crow[2], cofs[2]; size_t clds[2];
#pragma unroll
    for (int cc = 0; cc < 2; ++cc) {
        const int c = tid + cc * 512;
        crow[cc] = c >> 3;
        cofs[cc] = ((c & 7) ^ (crow[cc] & 7)) * 8;
        clds[cc] = (size_t)c * 16;
    }

#define STAGE_O(s, kt)                                                             \
    {                                                                              \
        _Pragma("unroll")                                                          \
        for (int cc = 0; cc < 2; ++cc) {                                           \
            __builtin_amdgcn_global_load_lds(                                      \
                (gaddr_t*)(ab + (size_t)(m0 + crow[cc]) * C_ + (kt) * 64 + cofs[cc]),  \
                (laddr_t*)((char*)As[s] + clds[cc]), 16, 0, 0);                    \
            __builtin_amdgcn_global_load_lds(                                      \
                (gaddr_t*)(wot + (size_t)(n0 + crow[cc]) * C_ + (kt) * 64 + cofs[cc]), \
                (laddr_t*)((char*)Bs[s] + clds[cc]), 16, 0, 0);                    \
        }                                                                          \
    }

    f32x4 acc[4][2] = {};
    constexpr int NT = C_ / 64;

    STAGE_O(0, 0);
    STAGE_O(1, 1);
    asm volatile("s_waitcnt vmcnt(4)" ::: "memory");
    __builtin_amdgcn_s_barrier();
    __builtin_amdgcn_sched_barrier(0);

    for (int t = 0; t < NT; ++t) {
        const int s = t % 3;
        if (t + 2 < NT) STAGE_O((t + 2) % 3, t + 2);

        const unsigned short* Ac = As[s];
        const unsigned short* Bc = Bs[s];
#pragma unroll
        for (int half = 0; half < 2; ++half) {
            bf16x8 af[4], bfv[2];
#pragma unroll
            for (int mt = 0; mt < 4; ++mt) {
                const int row = wm + mt * 16 + fr, dg = half * 4 + qd;
                af[mt] = *(const bf16x8*)&Ac[row * 64 + ((dg ^ (row & 7)) * 8)];
            }
#pragma unroll
            for (int nt = 0; nt < 2; ++nt) {
                const int row = wn2 + nt * 16 + fr, dg = half * 4 + qd;
                bfv[nt] = *(const bf16x8*)&Bc[row * 64 + ((dg ^ (row & 7)) * 8)];
            }
#pragma unroll
            for (int mt = 0; mt < 4; ++mt)
#pragma unroll
                for (int nt = 0; nt < 2; ++nt)
                    acc[mt][nt] = __builtin_amdgcn_mfma_f32_16x16x32_bf16(
                        bfv[nt], af[mt], acc[mt][nt], 0, 0, 0);
        }

        if (t + 2 < NT)      asm volatile("s_waitcnt vmcnt(4)" ::: "memory");
        else if (t + 1 < NT) asm volatile("s_waitcnt vmcnt(0)" ::: "memory");
        __builtin_amdgcn_s_barrier();
        __builtin_amdgcn_sched_barrier(0);
    }
#undef STAGE_O

#pragma unroll
    for (int mt = 0; mt < 4; ++mt) {
        const int mm = m0 + wm + mt * 16 + fr;
#pragma unroll
        for (int nt = 0; nt < 2; ++nt) {
            const int nn = n0 + wn2 + nt * 16 + qd * 4;
            const float4 b4 = *(const float4*)(bo + nn);
            *(float4*)(out + (size_t)mm * C_ + nn) =
                make_float4(acc[mt][nt][0] + b4.x, acc[mt][nt][1] + b4.y,
                            acc[mt][nt][2] + b4.z, acc[mt][nt][3] + b4.w);
        }
    }
}

// ---------------------------------------------------------------------------
// MFMA flash attention v8 — 512 threads: two 64-row wave-groups share one
// K/V stream (halves staging issues/CU), TRI-BUFFERED K/V with depth-2
// prefetch + counted vmcnt(2) (R6's proven GEMM pipeline mechanism).
// Causal structure = R5-verified: qr0 = qt*128 + w*16, jt_diag = qr0>>6,
// jtmax = 2qt+1 (fully-masked tiles contribute P=0).
// LDS 66.4 KB -> 2 blocks/CU = 16 waves/CU.
// ---------------------------------------------------------------------------
__global__ __launch_bounds__(512)
void attn_lds(const unsigned short* __restrict__ qb, const unsigned short* __restrict__ kb,
              const unsigned short* __restrict__ vtt, unsigned short* __restrict__ attb)
{
    __shared__ unsigned short Ks[3][64 * 64];      // 3 x 8 KB
    __shared__ unsigned short Vs[3][64 * 64];      // 3 x 8 KB
    __shared__ alignas(16) unsigned short Pt[8][16 * 72];   // 18.4 KB

    const int tid = threadIdx.x;
    const int lane = tid & 63, w = tid >> 6;       // w: 0..7
    const int fr = lane & 15, qd = lane >> 4;

    const int blk = blockIdx.x;                    // 512 blocks
    const int xcd = blk & 7, within = blk >> 3;    // within: 0..63
    const int bh = xcd * 4 + (within & 3);
    const int jj = within >> 2;                    // 0..15
    const int qt = (jj >> 3) == 0 ? (15 - (jj & 7)) : (jj & 7);   // heavy/light pairing
    const int b = bh >> 4, h = bh & 15;

    unsigned short* Pw = Pt[w];
    const unsigned short* qB = qb  + (size_t)bh * T_ * D_;
    const unsigned short* kB = kb  + (size_t)bh * T_ * D_;
    const unsigned short* vT = vtt + (size_t)bh * (T_ / 64) * 64 * 64;

    const int qr0 = qt * 128 + w * 16;             // this wave's 16 q-rows
    const int qrow_g = qr0 + fr;
    const int jtmax = 2 * qt + 1;                  // K-tiles 0..jtmax
    const int jt_diag = qr0 >> 6;                  // first tile touching diagonal

    bf16x8 aq0 = *(const bf16x8*)(qB + (size_t)(qr0 + fr) * D_ + qd * 8);
    bf16x8 aq1 = *(const bf16x8*)(qB + (size_t)(qr0 + fr) * D_ + 32 + qd * 8);

    f32x4 accT[4] = {};
    float l_i = 0.0f;
    const float sc2 = 0.18033688f;                 // log2(e) / sqrt(64)

    // 512 threads x 1 chunk each per 8 KB tile
    const int L0 = tid;
    const int r0 = L0 >> 3, e0 = (((L0 & 7) ^ (r0 & 7)) * 8);

#define STAGE_KV(s, jt)                                                            \
    {                                                                              \
        __builtin_amdgcn_global_load_lds(                                          \
            (gaddr_t*)(kB + (size_t)(jt) * 4096 + r0 * 64 + e0),                   \
            (laddr_t*)((char*)Ks[s] + (size_t)L0 * 16), 16, 0, 0);                 \
        __builtin_amdgcn_global_load_lds(                                          \
            (gaddr_t*)(vT + (size_t)(jt) * 4096 + r0 * 64 + e0),                   \
            (laddr_t*)((char*)Vs[s] + (size_t)L0 * 16), 16, 0, 0);                 \
    }

    STAGE_KV(0, 0);
    STAGE_KV(1, 1);
    asm volatile("s_waitcnt vmcnt(2)" ::: "memory");   // tile0 landed; tile1 in flight
    __builtin_amdgcn_s_barrier();
    __builtin_amdgcn_sched_barrier(0);

    for (int jt = 0; jt <= jtmax; ++jt) {
        const int s = jt % 3;
        if (jt + 2 <= jtmax) STAGE_KV((jt + 2) % 3, jt + 2);   // slot freed end of jt-1

        const unsigned short* Kc = Ks[s];
        const unsigned short* Vc = Vs[s];

        bf16x8 bk[8];
#pragma unroll
        for (int q8 = 0; q8 < 8; ++q8) {
            const int row = (q8 >> 1) * 16 + fr;
            const int dg = (q8 & 1) * 4 + qd;
            bk[q8] = *(const bf16x8*)&Kc[row * 64 + ((dg ^ (row & 7)) * 8)];
        }

        f32x4 s4[4] = {};
        __builtin_amdgcn_s_setprio(1);
#pragma unroll
        for (int nt = 0; nt < 4; ++nt) {
            s4[nt] = __builtin_amdgcn_mfma_f32_16x16x32_bf16(bk[nt * 2 + 0], aq0, s4[nt], 0, 0, 0);
            s4[nt] = __builtin_amdgcn_mfma_f32_16x16x32_bf16(bk[nt * 2 + 1], aq1, s4[nt], 0, 0, 0);
        }
        __builtin_amdgcn_s_setprio(0);

        if (jt >= jt_diag) {                       // diagonal or beyond: mask
            const int kbase = jt * 64 + qd * 4;
#pragma unroll
            for (int nt = 0; nt < 4; ++nt)
#pragma unroll
            for (int r = 0; r < 4; ++r) {
                const int kcol = kbase + nt * 16 + r;
                const float pv = (kcol <= qrow_g)
                               ? __builtin_amdgcn_exp2f(s4[nt][r] * sc2) : 0.0f;
                s4[nt][r] = pv;
                l_i += pv;
            }
        } else {
#pragma unroll
            for (int nt = 0; nt < 4; ++nt)
#pragma unroll
            for (int r = 0; r < 4; ++r) {
                const float pv = __builtin_amdgcn_exp2f(s4[nt][r] * sc2);
                s4[nt][r] = pv;
                l_i += pv;
            }
        }

#pragma unroll
        for (int nt = 0; nt < 4; ++nt) {
            union { __hip_bfloat162 h2[2]; unsigned long long u; } pk;
            pk.h2[0] = __float22bfloat162_rn(make_float2(s4[nt][0], s4[nt][1]));
            pk.h2[1] = __float22bfloat162_rn(make_float2(s4[nt][2], s4[nt][3]));
            *(unsigned long long*)&Pw[fr * 72 + nt * 16 + qd * 4] = pk.u;
        }
        const bf16x8 ap0 = *(const bf16x8*)&Pw[fr * 72 + qd * 8];
        const bf16x8 ap1 = *(const bf16x8*)&Pw[fr * 72 + 32 + qd * 8];

        bf16x8 bv[8];
#pragma unroll
        for (int q8 = 0; q8 < 8; ++q8) {
            const int row = (q8 >> 1) * 16 + fr;
            const int dg = (q8 & 1) * 4 + qd;
            bv[q8] = *(const bf16x8*)&Vc[row * 64 + ((dg ^ (row & 7)) * 8)];
        }

        __builtin_amdgcn_s_setprio(1);
#pragma unroll
        for (int nt = 0; nt < 4; ++nt) {
            accT[nt] = __builtin_amdgcn_mfma_f32_16x16x32_bf16(bv[nt * 2 + 0], ap0, accT[nt], 0, 0, 0);
            accT[nt] = __builtin_amdgcn_mfma_f32_16x16x32_bf16(bv[nt * 2 + 1], ap1, accT[nt], 0, 0, 0);
        }
        __builtin_amdgcn_s_setprio(0);

        // wait tile jt+1 (issued a full iteration ago); keep jt+2 in flight
        if (jt + 2 <= jtmax)      asm volatile("s_waitcnt vmcnt(2)" ::: "memory");
        else if (jt + 1 <= jtmax) asm volatile("s_waitcnt vmcnt(0)" ::: "memory");
        __builtin_amdgcn_s_barrier();
        __builtin_amdgcn_sched_barrier(0);
    }
#undef STAGE_KV

    l_i += __shfl_xor(l_i, 16);
    l_i += __shfl_xor(l_i, 32);
    const float inv = 1.0f / l_i;

#pragma unroll
    for (int nt = 0; nt < 4; ++nt) {
        union { __hip_bfloat162 h2[2]; unsigned long long u; } ok;
        ok.h2[0] = __float22bfloat162_rn(make_float2(accT[nt][0] * inv, accT[nt][1] * inv));
        ok.h2[1] = __float22bfloat162_rn(make_float2(accT[nt][2] * inv, accT[nt][3] * inv));
        *(unsigned long long*)&Pw[fr * 72 + nt * 16 + qd * 4] = ok.u;
    }
    {
        const int row = lane >> 2, d0 = (lane & 3) * 16;
        const bf16x8 o0 = *(const bf16x8*)&Pw[row * 72 + d0];
        const bf16x8 o1 = *(const bf16x8*)&Pw[row * 72 + d0 + 8];
        unsigned short* op = attb + ((size_t)b * T_ + qr0 + row) * C_ + h * 64 + d0;
        *(bf16x8*)op = o0;
        *(bf16x8*)(op + 8) = o1;
    }
}

// ---------------------------------------------------------------------------
// Fallback (ws too small for kb): per-wave kernel, fp32 K + tiled V^T.
// ---------------------------------------------------------------------------
__global__ __launch_bounds__(256)
void attn_v4(const unsigned short* __restrict__ qb, const float* __restrict__ kf,
             const unsigned short* __restrict__ vtt, unsigned short* __restrict__ attb)
{
    __shared__ alignas(16) unsigned short Pt[4][16 * 72];

    const int tid = threadIdx.x;
    const int lane = tid & 63, w = tid >> 6;
    const int fr = lane & 15, qd = lane >> 4;

    const int blk = blockIdx.x;
    const int xcd = blk & 7, within = blk >> 3;
    const int bh = xcd * 4 + (within & 3);
    const int jj = within >> 2;
    const int kk_ = jj >> 3, ii_ = jj & 7;
    const int qt = (kk_ == 0) ? (31 - ii_) : (kk_ == 1) ? ii_
                 : (kk_ == 2) ? (23 - ii_) : (8 + ii_);
    const int b = bh >> 4, h = bh & 15;

    unsigned short* Pw = Pt[w];
    const unsigned short* qB = qb  + (size_t)bh * T_ * D_;
    const float*          kB = kf  + (size_t)bh * T_ * D_;
    const unsigned short* vT = vtt + (size_t)bh * (T_ / 64) * 64 * 64;

    const int qr0 = qt * 64 + w * 16;
    const int qrow_g = qr0 + fr;

    bf16x8 aq0 = *(const bf16x8*)(qB + (size_t)(qr0 + fr) * D_ + qd * 8);
    bf16x8 aq1 = *(const bf16x8*)(qB + (size_t)(qr0 + fr) * D_ + 32 + qd * 8);

    f32x4 accT[4] = {};
    float l_i = 0.0f;
    const float sc2 = 0.18033688f;

    for (int jt = 0; jt <= qt; ++jt) {
        bf16x8 bk[8];
#pragma unroll
        for (int q8 = 0; q8 < 8; ++q8) {
            const float* p = kB + (size_t)(jt * 64 + (q8 >> 1) * 16 + fr) * D_
                           + (q8 & 1) * 32 + qd * 8;
            bk[q8] = cvt8(*(const float4*)p, *(const float4*)(p + 4));
        }
        f32x4 s4[4] = {};
#pragma unroll
        for (int nt = 0; nt < 4; ++nt) {
            s4[nt] = __builtin_amdgcn_mfma_f32_16x16x32_bf16(bk[nt * 2 + 0], aq0, s4[nt], 0, 0, 0);
            s4[nt] = __builtin_amdgcn_mfma_f32_16x16x32_bf16(bk[nt * 2 + 1], aq1, s4[nt], 0, 0, 0);
        }
        if (jt == qt) {
            const int kbase = jt * 64 + qd * 4;
#pragma unroll
            for (int nt = 0; nt < 4; ++nt)
#pragma unroll
            for (int r = 0; r < 4; ++r) {
                const int kcol = kbase + nt * 16 + r;
                const float pv = (kcol <= qrow_g)
                               ? __builtin_amdgcn_exp2f(s4[nt][r] * sc2) : 0.0f;
                s4[nt][r] = pv; l_i += pv;
            }
        } else {
#pragma unroll
            for (int nt = 0; nt < 4; ++nt)
#pragma unroll
            for (int r = 0; r < 4; ++r) {
                const float pv = __builtin_amdgcn_exp2f(s4[nt][r] * sc2);
                s4[nt][r] = pv; l_i += pv;
            }
        }
#pragma unroll
        for (int nt = 0; nt < 4; ++nt) {
            union { __hip_bfloat162 h2[2]; unsigned long long u; } pk;
            pk.h2[0] = __float22bfloat162_rn(make_float2(s4[nt][0], s4[nt][1]));
            pk.h2[1] = __float22bfloat162_rn(make_float2(s4[nt][2], s4[nt][3]));
            *(unsigned long long*)&Pw[fr * 72 + nt * 16 + qd * 4] = pk.u;
        }
        const bf16x8 ap0 = *(const bf16x8*)&Pw[fr * 72 + qd * 8];
        const bf16x8 ap1 = *(const bf16x8*)&Pw[fr * 72 + 32 + qd * 8];

        bf16x8 bv[8];
#pragma unroll
        for (int q8 = 0; q8 < 8; ++q8)
            bv[q8] = *(const bf16x8*)(vT + (size_t)jt * 4096
                                      + ((q8 >> 1) * 16 + fr) * 64 + (q8 & 1) * 32 + qd * 8);
#pragma unroll
        for (int nt = 0; nt < 4; ++nt) {
            accT[nt] = __builtin_amdgcn_mfma_f32_16x16x32_bf16(bv[nt * 2 + 0], ap0, accT[nt], 0, 0, 0);
            accT[nt] = __builtin_amdgcn_mfma_f32_16x16x32_bf16(bv[nt * 2 + 1], ap1, accT[nt], 0, 0, 0);
        }
    }

    l_i += __shfl_xor(l_i, 16);
    l_i += __shfl_xor(l_i, 32);
    const float inv = 1.0f / l_i;
#pragma unroll
    for (int nt = 0; nt < 4; ++nt) {
        union { __hip_bfloat162 h2[2]; unsigned long long u; } ok;
        ok.h2[0] = __float22bfloat162_rn(make_float2(accT[nt][0] * inv, accT[nt][1] * inv));
        ok.h2[1] = __float22bfloat162_rn(make_float2(accT[nt][2] * inv, accT[nt][3] * inv));
        *(unsigned long long*)&Pw[fr * 72 + nt * 16 + qd * 4] = ok.u;
    }
    {
        const int row = lane >> 2, d0 = (lane & 3) * 16;
        const bf16x8 o0 = *(const bf16x8*)&Pw[row * 72 + d0];
        const bf16x8 o1 = *(const bf16x8*)&Pw[row * 72 + d0 + 8];
        unsigned short* op = attb + ((size_t)b * T_ + qr0 + row) * C_ + h * 64 + d0;
        *(bf16x8*)op = o0;
        *(bf16x8*)(op + 8) = o1;
    }
}

// ---------------------------------------------------------------------------
extern "C" void kernel_launch(void* const* d_in, const int* in_sizes, int n_in,
                              void* d_out, int out_size, void* d_ws, size_t ws_size,
                              hipStream_t stream)
{
    (void)in_sizes; (void)n_in; (void)out_size;
    const float* x  = (const float*)d_in[0];
    const float* Wq = (const float*)d_in[1];
    const float* Wk = (const float*)d_in[2];
    const float* Wv = (const float*)d_in[3];
    const float* Wo = (const float*)d_in[4];
    const float* bo = (const float*)d_in[5];

    float* out  = (float*)d_out;                       // (B,T,C)
    float* kout = out  + (size_t)M_ * C_;              // (B,H,T,D) fp32
    float* vout = kout + (size_t)B_ * H_ * T_ * D_;    // (B,H,T,D) fp32

    // ws: xb(8M) | wtb(8M) | qb(8M) | vtt(8M) | kb(8M, optional); attb aliases xb
    unsigned short* xb   = (unsigned short*)d_ws;
    unsigned short* wtb  = xb  + (size_t)M_ * C_;
    unsigned short* qb   = wtb + (size_t)4 * C_ * C_;
    unsigned short* vtt  = qb  + (size_t)M_ * C_;
    unsigned short* kb   = vtt + (size_t)M_ * C_;
    unsigned short* attb = xb;
    const bool use_kb = ws_size >= (size_t)40 * 1024 * 1024;

    prep<<<dim3(16, 16, 5), 256, 0, stream>>>(x, Wq, Wk, Wv, Wo, xb, wtb);

    if (use_kb)
        gemm_qkv<1><<<dim3(24, 32), 512, 0, stream>>>(xb, wtb, qb, kout, vout, kb, vtt);
    else
        gemm_qkv<0><<<dim3(24, 32), 512, 0, stream>>>(xb, wtb, qb, kout, vout, kb, vtt);

    if (use_kb)
        attn_lds<<<512, 512, 0, stream>>>(qb, kb, vtt, attb);
    else
        attn_v4<<<1024, 256, 0, stream>>>(qb, kout, vtt, attb);

    gemm_o<<<dim3(8, 32), 512, 0, stream>>>(attb, wtb + (size_t)3 * C_ * C_, bo, out);
}

// Round 9
// 180.977 us; speedup vs baseline: 1.1022x; 1.0451x over previous
//
#include <hip/hip_runtime.h>
#include <hip/hip_bf16.h>

constexpr int B_ = 2;
constexpr int T_ = 2048;
constexpr int C_ = 1024;
constexpr int H_ = 16;
constexpr int D_ = 64;
constexpr int M_ = B_ * T_;   // 4096 rows

typedef __attribute__((ext_vector_type(8))) short bf16x8;   // 8 bf16 = 4 VGPRs
typedef __attribute__((ext_vector_type(4))) float f32x4;
typedef const __attribute__((address_space(1))) void gaddr_t;
typedef __attribute__((address_space(3))) void laddr_t;

__device__ __forceinline__ unsigned short f2bf(float f) {   // fp32 -> bf16 RNE
    unsigned u = __float_as_uint(f);
    return (unsigned short)((u + 0x7fffu + ((u >> 16) & 1u)) >> 16);
}

union BF8 { bf16x8 v; __hip_bfloat162 h[4]; };

__device__ __forceinline__ bf16x8 cvt8(const float4 a, const float4 b) {
    BF8 r;
    r.h[0] = __float22bfloat162_rn(make_float2(a.x, a.y));
    r.h[1] = __float22bfloat162_rn(make_float2(a.z, a.w));
    r.h[2] = __float22bfloat162_rn(make_float2(b.x, b.y));
    r.h[3] = __float22bfloat162_rn(make_float2(b.z, b.w));
    return r.v;
}

// ---------------------------------------------------------------------------
// prep: z<4 -> W (K x N fp32) -> Wt (N x K bf16); z==4 -> x fp32 -> xb bf16.
// ---------------------------------------------------------------------------
__global__ __launch_bounds__(256)
void prep(const float* __restrict__ x, const float* __restrict__ Wq,
          const float* __restrict__ Wk, const float* __restrict__ Wv,
          const float* __restrict__ Wo, unsigned short* __restrict__ xb,
          unsigned short* __restrict__ wtb)
{
    const int z = blockIdx.z;
    const int tid = threadIdx.x;

    if (z == 4) {                                   // x cast: 256 blocks handle 1M float4
        const int base = (blockIdx.y * 16 + blockIdx.x) * 4096 + tid;
#pragma unroll
        for (int i = 0; i < 16; ++i) {
            const int idx = base + i * 256;
            float4 v = ((const float4*)x)[idx];
            union { __hip_bfloat162 h[2]; ushort4 u; } o;
            o.h[0] = __float22bfloat162_rn(make_float2(v.x, v.y));
            o.h[1] = __float22bfloat162_rn(make_float2(v.z, v.w));
            ((ushort4*)xb)[idx] = o.u;
        }
        return;
    }

    __shared__ float tile[64][65];
    const float* W = (z == 0) ? Wq : (z == 1) ? Wk : (z == 2) ? Wv : Wo;
    unsigned short* O = wtb + (size_t)z * C_ * C_;

    const int n0 = blockIdx.x * 64, k0 = blockIdx.y * 64;
    const int r = tid >> 4, c4 = (tid & 15) * 4;

#pragma unroll
    for (int i = 0; i < 4; ++i) {
        const int kk = i * 16 + r;
        float4 v = *(const float4*)(W + (size_t)(k0 + kk) * C_ + n0 + c4);
        tile[c4 + 0][kk] = v.x;
        tile[c4 + 1][kk] = v.y;
        tile[c4 + 2][kk] = v.z;
        tile[c4 + 3][kk] = v.w;
    }
    __syncthreads();
#pragma unroll
    for (int i = 0; i < 4; ++i) {
        const int nn = i * 16 + r;
        ushort4 o;
        o.x = f2bf(tile[nn][c4 + 0]);
        o.y = f2bf(tile[nn][c4 + 1]);
        o.z = f2bf(tile[nn][c4 + 2]);
        o.w = f2bf(tile[nn][c4 + 3]);
        *(ushort4*)(O + (size_t)(n0 + nn) * C_ + k0 + c4) = o;
    }
}

// ---------------------------------------------------------------------------
// Fused QKV GEMM v4 — 128x192 tile over the CONTIGUOUS 3072-wide QKV weight
// block: grid = 32x16 = 512 blocks = EXACTLY 2 blocks/CU x 256 CUs, one full
// dispatch round (R6's 768 grid was 1.5 rounds — round 2 half-empty).
// 512 thr = 8 waves of 64x48 (28 FLOP/LDS-byte, up from 21). Double-buffered
// LDS (80 KB -> 2 blocks/CU, 16 waves/CU) with issue-top depth-1 prefetch +
// single bottom vmcnt(0)+barrier (R4-attn's proven race-free pattern).
// Epilogue derives which = nn>>10 per column (tiles may span q/k/v).
// ---------------------------------------------------------------------------
template<int WRITE_KB>
__global__ __launch_bounds__(512)
void gemm_qkv(const unsigned short* __restrict__ xb, const unsigned short* __restrict__ wtb,
              unsigned short* __restrict__ qb, float* __restrict__ kout,
              float* __restrict__ vout, unsigned short* __restrict__ kb,
              unsigned short* __restrict__ vtt)
{
    __shared__ unsigned short As[2][128 * 64];   // 2 x 16 KB
    __shared__ unsigned short Bs[2][192 * 64];   // 2 x 24 KB

    const int tid = threadIdx.x;
    const int n0g = blockIdx.x * 192;              // 0..2880 (over 3072)
    const int m0 = blockIdx.y * 128;

    const int lane = tid & 63, w = tid >> 6;       // w: 0..7
    const int wm = (w >> 2) * 64, wn = (w & 3) * 48;
    const int fr = lane & 15, qd = lane >> 4;

    // A: 1024 chunks (2/thread). B: 1536 chunks (3/thread).
    int arow[2], aofs[2]; size_t alds[2];
#pragma unroll
    for (int cc = 0; cc < 2; ++cc) {
        const int c = tid + cc * 512;
        arow[cc] = c >> 3;
        aofs[cc] = ((c & 7) ^ (arow[cc] & 7)) * 8;
        alds[cc] = (size_t)c * 16;
    }
    int brow[3], bofs[3]; size_t blds[3];
#pragma unroll
    for (int cc = 0; cc < 3; ++cc) {
        const int c = tid + cc * 512;
        brow[cc] = c >> 3;
        bofs[cc] = ((c & 7) ^ (brow[cc] & 7)) * 8;
        blds[cc] = (size_t)c * 16;
    }

#define STAGE(s, kt)                                                                   \
    {                                                                                  \
        _Pragma("unroll")                                                              \
        for (int cc = 0; cc < 2; ++cc)                                                 \
            __builtin_amdgcn_global_load_lds(                                          \
                (gaddr_t*)(xb + (size_t)(m0 + arow[cc]) * C_ + (kt) * 64 + aofs[cc]),  \
                (laddr_t*)((char*)As[s] + alds[cc]), 16, 0, 0);                        \
        _Pragma("unroll")                                                              \
        for (int cc = 0; cc < 3; ++cc)                                                 \
            __builtin_amdgcn_global_load_lds(                                          \
                (gaddr_t*)(wtb + (size_t)(n0g + brow[cc]) * C_ + (kt) * 64 + bofs[cc]),\
                (laddr_t*)((char*)Bs[s] + blds[cc]), 16, 0, 0);                        \
    }

    f32x4 acc[4][3] = {};
    constexpr int NT = C_ / 64;                    // 16 K-tiles

    STAGE(0, 0);
    asm volatile("s_waitcnt vmcnt(0)" ::: "memory");
    __builtin_amdgcn_s_barrier();
    __builtin_amdgcn_sched_barrier(0);

    for (int t = 0; t < NT; ++t) {
        const int s = t & 1;
        if (t + 1 < NT) STAGE(s ^ 1, t + 1);       // issue next tile at iter top

        const unsigned short* Ac = As[s];
        const unsigned short* Bc = Bs[s];
#pragma unroll
        for (int half = 0; half < 2; ++half) {
            bf16x8 af[4], bfv[3];
#pragma unroll
            for (int mt = 0; mt < 4; ++mt) {
                const int row = wm + mt * 16 + fr, dg = half * 4 + qd;
                af[mt] = *(const bf16x8*)&Ac[row * 64 + ((dg ^ (row & 7)) * 8)];
            }
#pragma unroll
            for (int nt = 0; nt < 3; ++nt) {
                const int row = wn + nt * 16 + fr, dg = half * 4 + qd;
                bfv[nt] = *(const bf16x8*)&Bc[row * 64 + ((dg ^ (row & 7)) * 8)];
            }
#pragma unroll
            for (int mt = 0; mt < 4; ++mt)
#pragma unroll
                for (int nt = 0; nt < 3; ++nt)
                    acc[mt][nt] = __builtin_amdgcn_mfma_f32_16x16x32_bf16(
                        bfv[nt], af[mt], acc[mt][nt], 0, 0, 0);
        }

        // next tile's loads had the whole body to land; buffer s is fully
        // consumed (each wave's MFMAs already waited on its own ds_reads).
        asm volatile("s_waitcnt vmcnt(0)" ::: "memory");
        __builtin_amdgcn_s_barrier();
        __builtin_amdgcn_sched_barrier(0);
    }
#undef STAGE

    // Flipped C/D layout: col(lane&15)=m token, row=(lane>>4)*4+reg = n feature
#pragma unroll
    for (int mt = 0; mt < 4; ++mt) {
        const int mm = m0 + wm + mt * 16 + fr;
        const int b = mm >> 11, t = mm & (T_ - 1);
#pragma unroll
        for (int nt = 0; nt < 3; ++nt) {
            const int nn = n0g + wn + nt * 16 + qd * 4;   // global col in 0..3071
            const int which = nn >> 10;                   // 0=q 1=k 2=v
            const int nw = nn & 1023;
            const int h = nw >> 6, d0 = nw & 63;
            const int bh = b * H_ + h;
            const size_t off = ((size_t)bh * T_ + t) * D_ + d0;
            const f32x4 a4 = acc[mt][nt];
            if (which == 0) {
                *(ushort4*)(qb + off) =
                    make_ushort4(f2bf(a4[0]), f2bf(a4[1]), f2bf(a4[2]), f2bf(a4[3]));
            } else if (which == 1) {
                *(float4*)(kout + off) = make_float4(a4[0], a4[1], a4[2], a4[3]);
                if (WRITE_KB)
                    *(ushort4*)(kb + off) =
                        make_ushort4(f2bf(a4[0]), f2bf(a4[1]), f2bf(a4[2]), f2bf(a4[3]));
            } else {
                *(float4*)(vout + off) = make_float4(a4[0], a4[1], a4[2], a4[3]);
                // fused V^T: vtt[bh][t>>6][d][t&63]
                unsigned short* vb = vtt
                    + (((size_t)bh * (T_ / 64) + (t >> 6)) * 64 + d0) * 64 + (t & 63);
#pragma unroll
                for (int r = 0; r < 4; ++r) vb[(size_t)r * 64] = f2bf(a4[r]);
            }
        }
    }
}

// ---------------------------------------------------------------------------
// Output projection — tri-buffer depth-2, 128x128, 512 threads (R6 config).
// ---------------------------------------------------------------------------
__global__ __launch_bounds__(512)
void gemm_o(const unsigned short* __restrict__ ab, const unsigned short* __restrict__ wot,
            const float* __restrict__ bo, float* __restrict__ out)
{
    __shared__ unsigned short As[3][128 * 64];
    __shared__ unsigned short Bs[3][128 * 64];

    const int tid = threadIdx.x;
    const int n0 = blockIdx.x * 128;
    const int m0 = blockIdx.y * 128;

    const int lane = tid & 63, w = tid >> 6;
    const int wm = (w >> 2) * 64, wn2 = (w & 3) * 32;
    const int fr = lane & 15, qd = lane >> 4;

    int crow[2], cofs[2]; size_t clds[2];
#pragma unroll
    for (int cc = 0; cc < 2; ++cc) {
        const int c = tid + cc * 512;
        crow[cc] = c >> 3;
        cofs[cc] = ((c & 7) ^ (crow[cc] & 7)) * 8;
        clds[cc] = (size_t)c * 16;
    }

#define STAGE_O(s, kt)                                                             \
    {                                                                              \
        _Pragma("unroll")                                                          \
        for (int cc = 0; cc < 2; ++cc) {                                           \
            __builtin_amdgcn_global_load_lds(                                      \
                (gaddr_t*)(ab + (size_t)(m0 + crow[cc]) * C_ + (kt) * 64 + cofs[cc]),  \
                (laddr_t*)((char*)As[s] + clds[cc]), 16, 0, 0);                    \
            __builtin_amdgcn_global_load_lds(                                      \
                (gaddr_t*)(wot + (size_t)(n0 + crow[cc]) * C_ + (kt) * 64 + cofs[cc]), \
                (laddr_t*)((char*)Bs[s] + clds[cc]), 16, 0, 0);                    \
        }                                                                          \
    }

    f32x4 acc[4][2] = {};
    constexpr int NT = C_ / 64;

    STAGE_O(0, 0);
    STAGE_O(1, 1);
    asm volatile("s_waitcnt vmcnt(4)" ::: "memory");
    __builtin_amdgcn_s_barrier();
    __builtin_amdgcn_sched_barrier(0);

    for (int t = 0; t < NT; ++t) {
        const int s = t % 3;
        if (t + 2 < NT) STAGE_O((t + 2) % 3, t + 2);

        const unsigned short* Ac = As[s];
        const unsigned short* Bc = Bs[s];
#pragma unroll
        for (int half = 0; half < 2; ++half) {
            bf16x8 af[4], bfv[2];
#pragma unroll
            for (int mt = 0; mt < 4; ++mt) {
                const int row = wm + mt * 16 + fr, dg = half * 4 + qd;
                af[mt] = *(const bf16x8*)&Ac[row * 64 + ((dg ^ (row & 7)) * 8)];
            }
#pragma unroll
            for (int nt = 0; nt < 2; ++nt) {
                const int row = wn2 + nt * 16 + fr, dg = half * 4 + qd;
                bfv[nt] = *(const bf16x8*)&Bc[row * 64 + ((dg ^ (row & 7)) * 8)];
            }
#pragma unroll
            for (int mt = 0; mt < 4; ++mt)
#pragma unroll
                for (int nt = 0; nt < 2; ++nt)
                    acc[mt][nt] = __builtin_amdgcn_mfma_f32_16x16x32_bf16(
                        bfv[nt], af[mt], acc[mt][nt], 0, 0, 0);
        }

        if (t + 2 < NT)      asm volatile("s_waitcnt vmcnt(4)" ::: "memory");
        else if (t + 1 < NT) asm volatile("s_waitcnt vmcnt(0)" ::: "memory");
        __builtin_amdgcn_s_barrier();
        __builtin_amdgcn_sched_barrier(0);
    }
#undef STAGE_O

#pragma unroll
    for (int mt = 0; mt < 4; ++mt) {
        const int mm = m0 + wm + mt * 16 + fr;
#pragma unroll
        for (int nt = 0; nt < 2; ++nt) {
            const int nn = n0 + wn2 + nt * 16 + qd * 4;
            const float4 b4 = *(const float4*)(bo + nn);
            *(float4*)(out + (size_t)mm * C_ + nn) =
                make_float4(acc[mt][nt][0] + b4.x, acc[mt][nt][1] + b4.y,
                            acc[mt][nt][2] + b4.z, acc[mt][nt][3] + b4.w);
        }
    }
}

// ---------------------------------------------------------------------------
// MFMA flash attention v6 — 64-row Q-tiles, double-buffered K/V (R6-exact,
// best-total config).
// ---------------------------------------------------------------------------
__global__ __launch_bounds__(256)
void attn_lds(const unsigned short* __restrict__ qb, const unsigned short* __restrict__ kb,
              const unsigned short* __restrict__ vtt, unsigned short* __restrict__ attb)
{
    __shared__ unsigned short Ks[2][64 * 64];
    __shared__ unsigned short Vs[2][64 * 64];
    __shared__ alignas(16) unsigned short Pt[4][16 * 72];

    const int tid = threadIdx.x;
    const int lane = tid & 63, w = tid >> 6;
    const int fr = lane & 15, qd = lane >> 4;

    const int blk = blockIdx.x;
    const int xcd = blk & 7, within = blk >> 3;      // within: 0..127
    const int bh = xcd * 4 + (within & 3);
    const int jj = within >> 2;                      // 0..31
    const int kk_ = jj >> 3, ii_ = jj & 7;
    const int qt = (kk_ == 0) ? (31 - ii_) : (kk_ == 1) ? ii_
                 : (kk_ == 2) ? (23 - ii_) : (8 + ii_);
    const int b = bh >> 4, h = bh & 15;

    unsigned short* Pw = Pt[w];
    const unsigned short* qB = qb  + (size_t)bh * T_ * D_;
    const unsigned short* kB = kb  + (size_t)bh * T_ * D_;
    const unsigned short* vT = vtt + (size_t)bh * (T_ / 64) * 64 * 64;

    const int qr0 = qt * 64 + w * 16;
    const int qrow_g = qr0 + fr;

    bf16x8 aq0 = *(const bf16x8*)(qB + (size_t)(qr0 + fr) * D_ + qd * 8);
    bf16x8 aq1 = *(const bf16x8*)(qB + (size_t)(qr0 + fr) * D_ + 32 + qd * 8);

    f32x4 accT[4] = {};
    float l_i = 0.0f;
    const float sc2 = 0.18033688f;                   // log2(e) / sqrt(64)

    const int L0 = w * 128 + lane, L1 = L0 + 64;
    const int r0 = L0 >> 3, e0 = (((L0 & 7) ^ (r0 & 7)) * 8);
    const int r1 = L1 >> 3, e1 = (((L1 & 7) ^ (r1 & 7)) * 8);

    // prologue: stage tile 0 into buffer 0
    {
        __builtin_amdgcn_global_load_lds((gaddr_t*)(kB + r0 * 64 + e0),
            (laddr_t*)((char*)Ks[0] + (size_t)L0 * 16), 16, 0, 0);
        __builtin_amdgcn_global_load_lds((gaddr_t*)(kB + r1 * 64 + e1),
            (laddr_t*)((char*)Ks[0] + (size_t)L1 * 16), 16, 0, 0);
        __builtin_amdgcn_global_load_lds((gaddr_t*)(vT + r0 * 64 + e0),
            (laddr_t*)((char*)Vs[0] + (size_t)L0 * 16), 16, 0, 0);
        __builtin_amdgcn_global_load_lds((gaddr_t*)(vT + r1 * 64 + e1),
            (laddr_t*)((char*)Vs[0] + (size_t)L1 * 16), 16, 0, 0);
    }
    asm volatile("s_waitcnt vmcnt(0)" ::: "memory");
    __builtin_amdgcn_s_barrier();
    __builtin_amdgcn_sched_barrier(0);

    for (int jt = 0; jt <= qt; ++jt) {
        const int cur = jt & 1;
        if (jt < qt) {                                // prefetch jt+1
            const unsigned short* kt = kB + (size_t)((jt + 1) * 64) * 64;
            const unsigned short* vt = vT + (size_t)(jt + 1) * 4096;
            char* Kn = (char*)Ks[cur ^ 1];
            char* Vn = (char*)Vs[cur ^ 1];
            __builtin_amdgcn_global_load_lds((gaddr_t*)(kt + r0 * 64 + e0),
                (laddr_t*)(Kn + (size_t)L0 * 16), 16, 0, 0);
            __builtin_amdgcn_global_load_lds((gaddr_t*)(kt + r1 * 64 + e1),
                (laddr_t*)(Kn + (size_t)L1 * 16), 16, 0, 0);
            __builtin_amdgcn_global_load_lds((gaddr_t*)(vt + r0 * 64 + e0),
                (laddr_t*)(Vn + (size_t)L0 * 16), 16, 0, 0);
            __builtin_amdgcn_global_load_lds((gaddr_t*)(vt + r1 * 64 + e1),
                (laddr_t*)(Vn + (size_t)L1 * 16), 16, 0, 0);
        }
        const unsigned short* Kc = Ks[cur];
        const unsigned short* Vc = Vs[cur];

        bf16x8 bk[8];
#pragma unroll
        for (int q8 = 0; q8 < 8; ++q8) {
            const int row = (q8 >> 1) * 16 + fr;
            const int dg = (q8 & 1) * 4 + qd;
            bk[q8] = *(const bf16x8*)&Kc[row * 64 + ((dg ^ (row & 7)) * 8)];
        }

        f32x4 s4[4] = {};
        __builtin_amdgcn_s_setprio(1);
#pragma unroll
        for (int nt = 0; nt < 4; ++nt) {
            s4[nt] = __builtin_amdgcn_mfma_f32_16x16x32_bf16(bk[nt * 2 + 0], aq0, s4[nt], 0, 0, 0);
            s4[nt] = __builtin_amdgcn_mfma_f32_16x16x32_bf16(bk[nt * 2 + 1], aq1, s4[nt], 0, 0, 0);
        }
        __builtin_amdgcn_s_setprio(0);

        if (jt == qt) {
            const int kbase = jt * 64 + qd * 4;
#pragma unroll
            for (int nt = 0; nt < 4; ++nt)
#pragma unroll
            for (int r = 0; r < 4; ++r) {
                const int kcol = kbase + nt * 16 + r;
                const float pv = (kcol <= qrow_g)
                               ? __builtin_amdgcn_exp2f(s4[nt][r] * sc2) : 0.0f;
                s4[nt][r] = pv;
                l_i += pv;
            }
        } else {
#pragma unroll
            for (int nt = 0; nt < 4; ++nt)
#pragma unroll
            for (int r = 0; r < 4; ++r) {
                const float pv = __builtin_amdgcn_exp2f(s4[nt][r] * sc2);
                s4[nt][r] = pv;
                l_i += pv;
            }
        }

#pragma unroll
        for (int nt = 0; nt < 4; ++nt) {
            union { __hip_bfloat162 h2[2]; unsigned long long u; } pk;
            pk.h2[0] = __float22bfloat162_rn(make_float2(s4[nt][0], s4[nt][1]));
            pk.h2[1] = __float22bfloat162_rn(make_float2(s4[nt][2], s4[nt][3]));
            *(unsigned long long*)&Pw[fr * 72 + nt * 16 + qd * 4] = pk.u;
        }
        const bf16x8 ap0 = *(const bf16x8*)&Pw[fr * 72 + qd * 8];
        const bf16x8 ap1 = *(const bf16x8*)&Pw[fr * 72 + 32 + qd * 8];

        bf16x8 bv[8];
#pragma unroll
        for (int q8 = 0; q8 < 8; ++q8) {
            const int row = (q8 >> 1) * 16 + fr;
            const int dg = (q8 & 1) * 4 + qd;
            bv[q8] = *(const bf16x8*)&Vc[row * 64 + ((dg ^ (row & 7)) * 8)];
        }

        __builtin_amdgcn_s_setprio(1);
#pragma unroll
        for (int nt = 0; nt < 4; ++nt) {
            accT[nt] = __builtin_amdgcn_mfma_f32_16x16x32_bf16(bv[nt * 2 + 0], ap0, accT[nt], 0, 0, 0);
            accT[nt] = __builtin_amdgcn_mfma_f32_16x16x32_bf16(bv[nt * 2 + 1], ap1, accT[nt], 0, 0, 0);
        }
        __builtin_amdgcn_s_setprio(0);

        // next tile's loads have had the whole body to land
        asm volatile("s_waitcnt vmcnt(0)" ::: "memory");
        __builtin_amdgcn_s_barrier();
        __builtin_amdgcn_sched_barrier(0);
    }

    l_i += __shfl_xor(l_i, 16);
    l_i += __shfl_xor(l_i, 32);
    const float inv = 1.0f / l_i;

#pragma unroll
    for (int nt = 0; nt < 4; ++nt) {
        union { __hip_bfloat162 h2[2]; unsigned long long u; } ok;
        ok.h2[0] = __float22bfloat162_rn(make_float2(accT[nt][0] * inv, accT[nt][1] * inv));
        ok.h2[1] = __float22bfloat162_rn(make_float2(accT[nt][2] * inv, accT[nt][3] * inv));
        *(unsigned long long*)&Pw[fr * 72 + nt * 16 + qd * 4] = ok.u;
    }
    {
        const int row = lane >> 2, d0 = (lane & 3) * 16;
        const bf16x8 o0 = *(const bf16x8*)&Pw[row * 72 + d0];
        const bf16x8 o1 = *(const bf16x8*)&Pw[row * 72 + d0 + 8];
        unsigned short* op = attb + ((size_t)b * T_ + qr0 + row) * C_ + h * 64 + d0;
        *(bf16x8*)op = o0;
        *(bf16x8*)(op + 8) = o1;
    }
}

// ---------------------------------------------------------------------------
// Fallback (ws too small for kb): per-wave kernel, fp32 K + tiled V^T.
// ---------------------------------------------------------------------------
__global__ __launch_bounds__(256)
void attn_v4(const unsigned short* __restrict__ qb, const float* __restrict__ kf,
             const unsigned short* __restrict__ vtt, unsigned short* __restrict__ attb)
{
    __shared__ alignas(16) unsigned short Pt[4][16 * 72];

    const int tid = threadIdx.x;
    const int lane = tid & 63, w = tid >> 6;
    const int fr = lane & 15, qd = lane >> 4;

    const int blk = blockIdx.x;
    const int xcd = blk & 7, within = blk >> 3;
    const int bh = xcd * 4 + (within & 3);
    const int jj = within >> 2;
    const int kk_ = jj >> 3, ii_ = jj & 7;
    const int qt = (kk_ == 0) ? (31 - ii_) : (kk_ == 1) ? ii_
                 : (kk_ == 2) ? (23 - ii_) : (8 + ii_);
    const int b = bh >> 4, h = bh & 15;

    unsigned short* Pw = Pt[w];
    const unsigned short* qB = qb  + (size_t)bh * T_ * D_;
    const float*          kB = kf  + (size_t)bh * T_ * D_;
    const unsigned short* vT = vtt + (size_t)bh * (T_ / 64) * 64 * 64;

    const int qr0 = qt * 64 + w * 16;
    const int qrow_g = qr0 + fr;

    bf16x8 aq0 = *(const bf16x8*)(qB + (size_t)(qr0 + fr) * D_ + qd * 8);
    bf16x8 aq1 = *(const bf16x8*)(qB + (size_t)(qr0 + fr) * D_ + 32 + qd * 8);

    f32x4 accT[4] = {};
    float l_i = 0.0f;
    const float sc2 = 0.18033688f;

    for (int jt = 0; jt <= qt; ++jt) {
        bf16x8 bk[8];
#pragma unroll
        for (int q8 = 0; q8 < 8; ++q8) {
            const float* p = kB + (size_t)(jt * 64 + (q8 >> 1) * 16 + fr) * D_
                           + (q8 & 1) * 32 + qd * 8;
            bk[q8] = cvt8(*(const float4*)p, *(const float4*)(p + 4));
        }
        f32x4 s4[4] = {};
#pragma unroll
        for (int nt = 0; nt < 4; ++nt) {
            s4[nt] = __builtin_amdgcn_mfma_f32_16x16x32_bf16(bk[nt * 2 + 0], aq0, s4[nt], 0, 0, 0);
            s4[nt] = __builtin_amdgcn_mfma_f32_16x16x32_bf16(bk[nt * 2 + 1], aq1, s4[nt], 0, 0, 0);
        }
        if (jt == qt) {
            const int kbase = jt * 64 + qd * 4;
#pragma unroll
            for (int nt = 0; nt < 4; ++nt)
#pragma unroll
            for (int r = 0; r < 4; ++r) {
                const int kcol = kbase + nt * 16 + r;
                const float pv = (kcol <= qrow_g)
                               ? __builtin_amdgcn_exp2f(s4[nt][r] * sc2) : 0.0f;
                s4[nt][r] = pv; l_i += pv;
            }
        } else {
#pragma unroll
            for (int nt = 0; nt < 4; ++nt)
#pragma unroll
            for (int r = 0; r < 4; ++r) {
                const float pv = __builtin_amdgcn_exp2f(s4[nt][r] * sc2);
                s4[nt][r] = pv; l_i += pv;
            }
        }
#pragma unroll
        for (int nt = 0; nt < 4; ++nt) {
            union { __hip_bfloat162 h2[2]; unsigned long long u; } pk;
            pk.h2[0] = __float22bfloat162_rn(make_float2(s4[nt][0], s4[nt][1]));
            pk.h2[1] = __float22bfloat162_rn(make_float2(s4[nt][2], s4[nt][3]));
            *(unsigned long long*)&Pw[fr * 72 + nt * 16 + qd * 4] = pk.u;
        }
        const bf16x8 ap0 = *(const bf16x8*)&Pw[fr * 72 + qd * 8];
        const bf16x8 ap1 = *(const bf16x8*)&Pw[fr * 72 + 32 + qd * 8];

        bf16x8 bv[8];
#pragma unroll
        for (int q8 = 0; q8 < 8; ++q8)
            bv[q8] = *(const bf16x8*)(vT + (size_t)jt * 4096
                                      + ((q8 >> 1) * 16 + fr) * 64 + (q8 & 1) * 32 + qd * 8);
#pragma unroll
        for (int nt = 0; nt < 4; ++nt) {
            accT[nt] = __builtin_amdgcn_mfma_f32_16x16x32_bf16(bv[nt * 2 + 0], ap0, accT[nt], 0, 0, 0);
            accT[nt] = __builtin_amdgcn_mfma_f32_16x16x32_bf16(bv[nt * 2 + 1], ap1, accT[nt], 0, 0, 0);
        }
    }

    l_i += __shfl_xor(l_i, 16);
    l_i += __shfl_xor(l_i, 32);
    const float inv = 1.0f / l_i;
#pragma unroll
    for (int nt = 0; nt < 4; ++nt) {
        union { __hip_bfloat162 h2[2]; unsigned long long u; } ok;
        ok.h2[0] = __float22bfloat162_rn(make_float2(accT[nt][0] * inv, accT[nt][1] * inv));
        ok.h2[1] = __float22bfloat162_rn(make_float2(accT[nt][2] * inv, accT[nt][3] * inv));
        *(unsigned long long*)&Pw[fr * 72 + nt * 16 + qd * 4] = ok.u;
    }
    {
        const int row = lane >> 2, d0 = (lane & 3) * 16;
        const bf16x8 o0 = *(const bf16x8*)&Pw[row * 72 + d0];
        const bf16x8 o1 = *(const bf16x8*)&Pw[row * 72 + d0 + 8];
        unsigned short* op = attb + ((size_t)b * T_ + qr0 + row) * C_ + h * 64 + d0;
        *(bf16x8*)op = o0;
        *(bf16x8*)(op + 8) = o1;
    }
}

// ---------------------------------------------------------------------------
extern "C" void kernel_launch(void* const* d_in, const int* in_sizes, int n_in,
                              void* d_out, int out_size, void* d_ws, size_t ws_size,
                              hipStream_t stream)
{
    (void)in_sizes; (void)n_in; (void)out_size;
    const float* x  = (const float*)d_in[0];
    const float* Wq = (const float*)d_in[1];
    const float* Wk = (const float*)d_in[2];
    const float* Wv = (const float*)d_in[3];
    const float* Wo = (const float*)d_in[4];
    const float* bo = (const float*)d_in[5];

    float* out  = (float*)d_out;                       // (B,T,C)
    float* kout = out  + (size_t)M_ * C_;              // (B,H,T,D) fp32
    float* vout = kout + (size_t)B_ * H_ * T_ * D_;    // (B,H,T,D) fp32

    // ws: xb(8M) | wtb(8M) | qb(8M) | vtt(8M) | kb(8M, optional); attb aliases xb
    unsigned short* xb   = (unsigned short*)d_ws;
    unsigned short* wtb  = xb  + (size_t)M_ * C_;
    unsigned short* qb   = wtb + (size_t)4 * C_ * C_;
    unsigned short* vtt  = qb  + (size_t)M_ * C_;
    unsigned short* kb   = vtt + (size_t)M_ * C_;
    unsigned short* attb = xb;
    const bool use_kb = ws_size >= (size_t)40 * 1024 * 1024;

    prep<<<dim3(16, 16, 5), 256, 0, stream>>>(x, Wq, Wk, Wv, Wo, xb, wtb);

    if (use_kb)
        gemm_qkv<1><<<dim3(16, 32), 512, 0, stream>>>(xb, wtb, qb, kout, vout, kb, vtt);
    else
        gemm_qkv<0><<<dim3(16, 32), 512, 0, stream>>>(xb, wtb, qb, kout, vout, kb, vtt);

    if (use_kb)
        attn_lds<<<1024, 256, 0, stream>>>(qb, kb, vtt, attb);
    else
        attn_v4<<<1024, 256, 0, stream>>>(qb, kout, vtt, attb);

    gemm_o<<<dim3(8, 32), 512, 0, stream>>>(attb, wtb + (size_t)3 * C_ * C_, bo, out);
}

// Round 10
// 176.436 us; speedup vs baseline: 1.1306x; 1.0257x over previous
//
#include <hip/hip_runtime.h>
#include <hip/hip_bf16.h>

constexpr int B_ = 2;
constexpr int T_ = 2048;
constexpr int C_ = 1024;
constexpr int H_ = 16;
constexpr int D_ = 64;
constexpr int M_ = B_ * T_;   // 4096 rows

typedef __attribute__((ext_vector_type(8))) short bf16x8;   // 8 bf16 = 4 VGPRs
typedef __attribute__((ext_vector_type(4))) float f32x4;
typedef const __attribute__((address_space(1))) void gaddr_t;
typedef __attribute__((address_space(3))) void laddr_t;

__device__ __forceinline__ unsigned short f2bf(float f) {   // fp32 -> bf16 RNE
    unsigned u = __float_as_uint(f);
    return (unsigned short)((u + 0x7fffu + ((u >> 16) & 1u)) >> 16);
}

union BF8 { bf16x8 v; __hip_bfloat162 h[4]; };

__device__ __forceinline__ bf16x8 cvt8(const float4 a, const float4 b) {
    BF8 r;
    r.h[0] = __float22bfloat162_rn(make_float2(a.x, a.y));
    r.h[1] = __float22bfloat162_rn(make_float2(a.z, a.w));
    r.h[2] = __float22bfloat162_rn(make_float2(b.x, b.y));
    r.h[3] = __float22bfloat162_rn(make_float2(b.z, b.w));
    return r.v;
}

// ---------------------------------------------------------------------------
// prep: z<4 -> W (K x N fp32) -> Wt (N x K bf16); z==4 -> x fp32 -> xb bf16.
// ---------------------------------------------------------------------------
__global__ __launch_bounds__(256)
void prep(const float* __restrict__ x, const float* __restrict__ Wq,
          const float* __restrict__ Wk, const float* __restrict__ Wv,
          const float* __restrict__ Wo, unsigned short* __restrict__ xb,
          unsigned short* __restrict__ wtb)
{
    const int z = blockIdx.z;
    const int tid = threadIdx.x;

    if (z == 4) {                                   // x cast: 256 blocks handle 1M float4
        const int base = (blockIdx.y * 16 + blockIdx.x) * 4096 + tid;
#pragma unroll
        for (int i = 0; i < 16; ++i) {
            const int idx = base + i * 256;
            float4 v = ((const float4*)x)[idx];
            union { __hip_bfloat162 h[2]; ushort4 u; } o;
            o.h[0] = __float22bfloat162_rn(make_float2(v.x, v.y));
            o.h[1] = __float22bfloat162_rn(make_float2(v.z, v.w));
            ((ushort4*)xb)[idx] = o.u;
        }
        return;
    }

    __shared__ float tile[64][65];
    const float* W = (z == 0) ? Wq : (z == 1) ? Wk : (z == 2) ? Wv : Wo;
    unsigned short* O = wtb + (size_t)z * C_ * C_;

    const int n0 = blockIdx.x * 64, k0 = blockIdx.y * 64;
    const int r = tid >> 4, c4 = (tid & 15) * 4;

#pragma unroll
    for (int i = 0; i < 4; ++i) {
        const int kk = i * 16 + r;
        float4 v = *(const float4*)(W + (size_t)(k0 + kk) * C_ + n0 + c4);
        tile[c4 + 0][kk] = v.x;
        tile[c4 + 1][kk] = v.y;
        tile[c4 + 2][kk] = v.z;
        tile[c4 + 3][kk] = v.w;
    }
    __syncthreads();
#pragma unroll
    for (int i = 0; i < 4; ++i) {
        const int nn = i * 16 + r;
        ushort4 o;
        o.x = f2bf(tile[nn][c4 + 0]);
        o.y = f2bf(tile[nn][c4 + 1]);
        o.z = f2bf(tile[nn][c4 + 2]);
        o.w = f2bf(tile[nn][c4 + 3]);
        *(ushort4*)(O + (size_t)(n0 + nn) * C_ + k0 + c4) = o;
    }
}

// ---------------------------------------------------------------------------
// Fused QKV GEMM v4 — 128x192 tile over the CONTIGUOUS 3072-wide QKV weight
// block: grid 512 = exactly 2 blocks/CU, one full dispatch round (R9 win).
// Q-epilogue PRE-SCALES by log2(e)/sqrt(D): attn's per-tile 16 muls vanish.
// ---------------------------------------------------------------------------
template<int WRITE_KB>
__global__ __launch_bounds__(512)
void gemm_qkv(const unsigned short* __restrict__ xb, const unsigned short* __restrict__ wtb,
              unsigned short* __restrict__ qb, float* __restrict__ kout,
              float* __restrict__ vout, unsigned short* __restrict__ kb,
              unsigned short* __restrict__ vtt)
{
    __shared__ unsigned short As[2][128 * 64];   // 2 x 16 KB
    __shared__ unsigned short Bs[2][192 * 64];   // 2 x 24 KB

    const int tid = threadIdx.x;
    const int n0g = blockIdx.x * 192;              // 0..2880 (over 3072)
    const int m0 = blockIdx.y * 128;

    const int lane = tid & 63, w = tid >> 6;       // w: 0..7
    const int wm = (w >> 2) * 64, wn = (w & 3) * 48;
    const int fr = lane & 15, qd = lane >> 4;

    // A: 1024 chunks (2/thread). B: 1536 chunks (3/thread).
    int arow[2], aofs[2]; size_t alds[2];
#pragma unroll
    for (int cc = 0; cc < 2; ++cc) {
        const int c = tid + cc * 512;
        arow[cc] = c >> 3;
        aofs[cc] = ((c & 7) ^ (arow[cc] & 7)) * 8;
        alds[cc] = (size_t)c * 16;
    }
    int brow[3], bofs[3]; size_t blds[3];
#pragma unroll
    for (int cc = 0; cc < 3; ++cc) {
        const int c = tid + cc * 512;
        brow[cc] = c >> 3;
        bofs[cc] = ((c & 7) ^ (brow[cc] & 7)) * 8;
        blds[cc] = (size_t)c * 16;
    }

#define STAGE(s, kt)                                                                   \
    {                                                                                  \
        _Pragma("unroll")                                                              \
        for (int cc = 0; cc < 2; ++cc)                                                 \
            __builtin_amdgcn_global_load_lds(                                          \
                (gaddr_t*)(xb + (size_t)(m0 + arow[cc]) * C_ + (kt) * 64 + aofs[cc]),  \
                (laddr_t*)((char*)As[s] + alds[cc]), 16, 0, 0);                        \
        _Pragma("unroll")                                                              \
        for (int cc = 0; cc < 3; ++cc)                                                 \
            __builtin_amdgcn_global_load_lds(                                          \
                (gaddr_t*)(wtb + (size_t)(n0g + brow[cc]) * C_ + (kt) * 64 + bofs[cc]),\
                (laddr_t*)((char*)Bs[s] + blds[cc]), 16, 0, 0);                        \
    }

    f32x4 acc[4][3] = {};
    constexpr int NT = C_ / 64;                    // 16 K-tiles

    STAGE(0, 0);
    asm volatile("s_waitcnt vmcnt(0)" ::: "memory");
    __builtin_amdgcn_s_barrier();
    __builtin_amdgcn_sched_barrier(0);

    for (int t = 0; t < NT; ++t) {
        const int s = t & 1;
        if (t + 1 < NT) STAGE(s ^ 1, t + 1);       // issue next tile at iter top

        const unsigned short* Ac = As[s];
        const unsigned short* Bc = Bs[s];
#pragma unroll
        for (int half = 0; half < 2; ++half) {
            bf16x8 af[4], bfv[3];
#pragma unroll
            for (int mt = 0; mt < 4; ++mt) {
                const int row = wm + mt * 16 + fr, dg = half * 4 + qd;
                af[mt] = *(const bf16x8*)&Ac[row * 64 + ((dg ^ (row & 7)) * 8)];
            }
#pragma unroll
            for (int nt = 0; nt < 3; ++nt) {
                const int row = wn + nt * 16 + fr, dg = half * 4 + qd;
                bfv[nt] = *(const bf16x8*)&Bc[row * 64 + ((dg ^ (row & 7)) * 8)];
            }
#pragma unroll
            for (int mt = 0; mt < 4; ++mt)
#pragma unroll
                for (int nt = 0; nt < 3; ++nt)
                    acc[mt][nt] = __builtin_amdgcn_mfma_f32_16x16x32_bf16(
                        bfv[nt], af[mt], acc[mt][nt], 0, 0, 0);
        }

        asm volatile("s_waitcnt vmcnt(0)" ::: "memory");
        __builtin_amdgcn_s_barrier();
        __builtin_amdgcn_sched_barrier(0);
    }
#undef STAGE

    const float SC2 = 0.18033688f;                 // log2(e)/sqrt(64), folded into q
    // Flipped C/D layout: col(lane&15)=m token, row=(lane>>4)*4+reg = n feature
#pragma unroll
    for (int mt = 0; mt < 4; ++mt) {
        const int mm = m0 + wm + mt * 16 + fr;
        const int b = mm >> 11, t = mm & (T_ - 1);
#pragma unroll
        for (int nt = 0; nt < 3; ++nt) {
            const int nn = n0g + wn + nt * 16 + qd * 4;   // global col in 0..3071
            const int which = nn >> 10;                   // 0=q 1=k 2=v
            const int nw = nn & 1023;
            const int h = nw >> 6, d0 = nw & 63;
            const int bh = b * H_ + h;
            const size_t off = ((size_t)bh * T_ + t) * D_ + d0;
            const f32x4 a4 = acc[mt][nt];
            if (which == 0) {
                *(ushort4*)(qb + off) =
                    make_ushort4(f2bf(a4[0] * SC2), f2bf(a4[1] * SC2),
                                 f2bf(a4[2] * SC2), f2bf(a4[3] * SC2));
            } else if (which == 1) {
                *(float4*)(kout + off) = make_float4(a4[0], a4[1], a4[2], a4[3]);
                if (WRITE_KB)
                    *(ushort4*)(kb + off) =
                        make_ushort4(f2bf(a4[0]), f2bf(a4[1]), f2bf(a4[2]), f2bf(a4[3]));
            } else {
                *(float4*)(vout + off) = make_float4(a4[0], a4[1], a4[2], a4[3]);
                // fused V^T: vtt[bh][t>>6][d][t&63]
                unsigned short* vb = vtt
                    + (((size_t)bh * (T_ / 64) + (t >> 6)) * 64 + d0) * 64 + (t & 63);
#pragma unroll
                for (int r = 0; r < 4; ++r) vb[(size_t)r * 64] = f2bf(a4[r]);
            }
        }
    }
}

// ---------------------------------------------------------------------------
// Output projection — tri-buffer depth-2, 128x128, 512 threads (R6 config).
// ---------------------------------------------------------------------------
__global__ __launch_bounds__(512)
void gemm_o(const unsigned short* __restrict__ ab, const unsigned short* __restrict__ wot,
            const float* __restrict__ bo, float* __restrict__ out)
{
    __shared__ unsigned short As[3][128 * 64];
    __shared__ unsigned short Bs[3][128 * 64];

    const int tid = threadIdx.x;
    const int n0 = blockIdx.x * 128;
    const int m0 = blockIdx.y * 128;

    const int lane = tid & 63, w = tid >> 6;
    const int wm = (w >> 2) * 64, wn2 = (w & 3) * 32;
    const int fr = lane & 15, qd = lane >> 4;

    int crow[2], cofs[2]; size_t clds[2];
#pragma unroll
    for (int cc = 0; cc < 2; ++cc) {
        const int c = tid + cc * 512;
        crow[cc] = c >> 3;
        cofs[cc] = ((c & 7) ^ (crow[cc] & 7)) * 8;
        clds[cc] = (size_t)c * 16;
    }

#define STAGE_O(s, kt)                                                             \
    {                                                                              \
        _Pragma("unroll")                                                          \
        for (int cc = 0; cc < 2; ++cc) {                                           \
            __builtin_amdgcn_global_load_lds(                                      \
                (gaddr_t*)(ab + (size_t)(m0 + crow[cc]) * C_ + (kt) * 64 + cofs[cc]),  \
                (laddr_t*)((char*)As[s] + clds[cc]), 16, 0, 0);                    \
            __builtin_amdgcn_global_load_lds(                                      \
                (gaddr_t*)(wot + (size_t)(n0 + crow[cc]) * C_ + (kt) * 64 + cofs[cc]), \
                (laddr_t*)((char*)Bs[s] + clds[cc]), 16, 0, 0);                    \
        }                                                                          \
    }

    f32x4 acc[4][2] = {};
    constexpr int NT = C_ / 64;

    STAGE_O(0, 0);
    STAGE_O(1, 1);
    asm volatile("s_waitcnt vmcnt(4)" ::: "memory");
    __builtin_amdgcn_s_barrier();
    __builtin_amdgcn_sched_barrier(0);

    for (int t = 0; t < NT; ++t) {
        const int s = t % 3;
        if (t + 2 < NT) STAGE_O((t + 2) % 3, t + 2);

        const unsigned short* Ac = As[s];
        const unsigned short* Bc = Bs[s];
#pragma unroll
        for (int half = 0; half < 2; ++half) {
            bf16x8 af[4], bfv[2];
#pragma unroll
            for (int mt = 0; mt < 4; ++mt) {
                const int row = wm + mt * 16 + fr, dg = half * 4 + qd;
                af[mt] = *(const bf16x8*)&Ac[row * 64 + ((dg ^ (row & 7)) * 8)];
            }
#pragma unroll
            for (int nt = 0; nt < 2; ++nt) {
                const int row = wn2 + nt * 16 + fr, dg = half * 4 + qd;
                bfv[nt] = *(const bf16x8*)&Bc[row * 64 + ((dg ^ (row & 7)) * 8)];
            }
#pragma unroll
            for (int mt = 0; mt < 4; ++mt)
#pragma unroll
                for (int nt = 0; nt < 2; ++nt)
                    acc[mt][nt] = __builtin_amdgcn_mfma_f32_16x16x32_bf16(
                        bfv[nt], af[mt], acc[mt][nt], 0, 0, 0);
        }

        if (t + 2 < NT)      asm volatile("s_waitcnt vmcnt(4)" ::: "memory");
        else if (t + 1 < NT) asm volatile("s_waitcnt vmcnt(0)" ::: "memory");
        __builtin_amdgcn_s_barrier();
        __builtin_amdgcn_sched_barrier(0);
    }
#undef STAGE_O

#pragma unroll
    for (int mt = 0; mt < 4; ++mt) {
        const int mm = m0 + wm + mt * 16 + fr;
#pragma unroll
        for (int nt = 0; nt < 2; ++nt) {
            const int nn = n0 + wn2 + nt * 16 + qd * 4;
            const float4 b4 = *(const float4*)(bo + nn);
            *(float4*)(out + (size_t)mm * C_ + nn) =
                make_float4(acc[mt][nt][0] + b4.x, acc[mt][nt][1] + b4.y,
                            acc[mt][nt][2] + b4.z, acc[mt][nt][3] + b4.w);
        }
    }
}

// ---------------------------------------------------------------------------
// MFMA flash attention v9 — VALU-debloat: (1) q pre-scaled in gemm_qkv (no
// per-tile sc2 muls); (2) l_i via MFMA-ones colsum (2 extra MFMA replace
// 16 VALU adds/iter + the final shfl pair); (3) heavy-first dispatch
// (qt = 31-jj) so the tail blocks are the 1-iteration ones.
// ---------------------------------------------------------------------------
__global__ __launch_bounds__(256)
void attn_lds(const unsigned short* __restrict__ qb, const unsigned short* __restrict__ kb,
              const unsigned short* __restrict__ vtt, unsigned short* __restrict__ attb)
{
    __shared__ unsigned short Ks[2][64 * 64];
    __shared__ unsigned short Vs[2][64 * 64];
    __shared__ alignas(16) unsigned short Pt[4][16 * 72];

    const int tid = threadIdx.x;
    const int lane = tid & 63, w = tid >> 6;
    const int fr = lane & 15, qd = lane >> 4;

    const int blk = blockIdx.x;
    const int xcd = blk & 7, within = blk >> 3;      // within: 0..127
    const int bh = xcd * 4 + (within & 3);
    const int jj = within >> 2;                      // 0..31
    const int qt = 31 - jj;                          // heavy-first
    const int b = bh >> 4, h = bh & 15;

    unsigned short* Pw = Pt[w];
    const unsigned short* qB = qb  + (size_t)bh * T_ * D_;
    const unsigned short* kB = kb  + (size_t)bh * T_ * D_;
    const unsigned short* vT = vtt + (size_t)bh * (T_ / 64) * 64 * 64;

    const int qr0 = qt * 64 + w * 16;
    const int qrow_g = qr0 + fr;

    bf16x8 aq0 = *(const bf16x8*)(qB + (size_t)(qr0 + fr) * D_ + qd * 8);
    bf16x8 aq1 = *(const bf16x8*)(qB + (size_t)(qr0 + fr) * D_ + 32 + qd * 8);

    const short one_bf = (short)0x3F80;              // bf16 1.0
    const bf16x8 ones8 = {one_bf, one_bf, one_bf, one_bf,
                          one_bf, one_bf, one_bf, one_bf};

    f32x4 accT[4] = {};
    f32x4 accL = {};                                 // MFMA-ones colsum of P

    const int L0 = w * 128 + lane, L1 = L0 + 64;
    const int r0 = L0 >> 3, e0 = (((L0 & 7) ^ (r0 & 7)) * 8);
    const int r1 = L1 >> 3, e1 = (((L1 & 7) ^ (r1 & 7)) * 8);

    // prologue: stage tile 0 into buffer 0
    {
        __builtin_amdgcn_global_load_lds((gaddr_t*)(kB + r0 * 64 + e0),
            (laddr_t*)((char*)Ks[0] + (size_t)L0 * 16), 16, 0, 0);
        __builtin_amdgcn_global_load_lds((gaddr_t*)(kB + r1 * 64 + e1),
            (laddr_t*)((char*)Ks[0] + (size_t)L1 * 16), 16, 0, 0);
        __builtin_amdgcn_global_load_lds((gaddr_t*)(vT + r0 * 64 + e0),
            (laddr_t*)((char*)Vs[0] + (size_t)L0 * 16), 16, 0, 0);
        __builtin_amdgcn_global_load_lds((gaddr_t*)(vT + r1 * 64 + e1),
            (laddr_t*)((char*)Vs[0] + (size_t)L1 * 16), 16, 0, 0);
    }
    asm volatile("s_waitcnt vmcnt(0)" ::: "memory");
    __builtin_amdgcn_s_barrier();
    __builtin_amdgcn_sched_barrier(0);

    for (int jt = 0; jt <= qt; ++jt) {
        const int cur = jt & 1;
        if (jt < qt) {                                // prefetch jt+1
            const unsigned short* kt = kB + (size_t)((jt + 1) * 64) * 64;
            const unsigned short* vt = vT + (size_t)(jt + 1) * 4096;
            char* Kn = (char*)Ks[cur ^ 1];
            char* Vn = (char*)Vs[cur ^ 1];
            __builtin_amdgcn_global_load_lds((gaddr_t*)(kt + r0 * 64 + e0),
                (laddr_t*)(Kn + (size_t)L0 * 16), 16, 0, 0);
            __builtin_amdgcn_global_load_lds((gaddr_t*)(kt + r1 * 64 + e1),
                (laddr_t*)(Kn + (size_t)L1 * 16), 16, 0, 0);
            __builtin_amdgcn_global_load_lds((gaddr_t*)(vt + r0 * 64 + e0),
                (laddr_t*)(Vn + (size_t)L0 * 16), 16, 0, 0);
            __builtin_amdgcn_global_load_lds((gaddr_t*)(vt + r1 * 64 + e1),
                (laddr_t*)(Vn + (size_t)L1 * 16), 16, 0, 0);
        }
        const unsigned short* Kc = Ks[cur];
        const unsigned short* Vc = Vs[cur];

        bf16x8 bk[8];
#pragma unroll
        for (int q8 = 0; q8 < 8; ++q8) {
            const int row = (q8 >> 1) * 16 + fr;
            const int dg = (q8 & 1) * 4 + qd;
            bk[q8] = *(const bf16x8*)&Kc[row * 64 + ((dg ^ (row & 7)) * 8)];
        }

        f32x4 s4[4] = {};
        __builtin_amdgcn_s_setprio(1);
#pragma unroll
        for (int nt = 0; nt < 4; ++nt) {
            s4[nt] = __builtin_amdgcn_mfma_f32_16x16x32_bf16(bk[nt * 2 + 0], aq0, s4[nt], 0, 0, 0);
            s4[nt] = __builtin_amdgcn_mfma_f32_16x16x32_bf16(bk[nt * 2 + 1], aq1, s4[nt], 0, 0, 0);
        }
        __builtin_amdgcn_s_setprio(0);

        if (jt == qt) {                               // diagonal: mask
            const int kbase = jt * 64 + qd * 4;
#pragma unroll
            for (int nt = 0; nt < 4; ++nt)
#pragma unroll
            for (int r = 0; r < 4; ++r) {
                const int kcol = kbase + nt * 16 + r;
                s4[nt][r] = (kcol <= qrow_g)
                          ? __builtin_amdgcn_exp2f(s4[nt][r]) : 0.0f;
            }
        } else {
#pragma unroll
            for (int nt = 0; nt < 4; ++nt)
#pragma unroll
            for (int r = 0; r < 4; ++r)
                s4[nt][r] = __builtin_amdgcn_exp2f(s4[nt][r]);
        }

#pragma unroll
        for (int nt = 0; nt < 4; ++nt) {
            union { __hip_bfloat162 h2[2]; unsigned long long u; } pk;
            pk.h2[0] = __float22bfloat162_rn(make_float2(s4[nt][0], s4[nt][1]));
            pk.h2[1] = __float22bfloat162_rn(make_float2(s4[nt][2], s4[nt][3]));
            *(unsigned long long*)&Pw[fr * 72 + nt * 16 + qd * 4] = pk.u;
        }
        const bf16x8 ap0 = *(const bf16x8*)&Pw[fr * 72 + qd * 8];
        const bf16x8 ap1 = *(const bf16x8*)&Pw[fr * 72 + 32 + qd * 8];

        bf16x8 bv[8];
#pragma unroll
        for (int q8 = 0; q8 < 8; ++q8) {
            const int row = (q8 >> 1) * 16 + fr;
            const int dg = (q8 & 1) * 4 + qd;
            bv[q8] = *(const bf16x8*)&Vc[row * 64 + ((dg ^ (row & 7)) * 8)];
        }

        __builtin_amdgcn_s_setprio(1);
#pragma unroll
        for (int nt = 0; nt < 4; ++nt) {
            accT[nt] = __builtin_amdgcn_mfma_f32_16x16x32_bf16(bv[nt * 2 + 0], ap0, accT[nt], 0, 0, 0);
            accT[nt] = __builtin_amdgcn_mfma_f32_16x16x32_bf16(bv[nt * 2 + 1], ap1, accT[nt], 0, 0, 0);
        }
        // l_i colsum rides the matrix pipe: every lane's accL = full row-sum
        accL = __builtin_amdgcn_mfma_f32_16x16x32_bf16(ones8, ap0, accL, 0, 0, 0);
        accL = __builtin_amdgcn_mfma_f32_16x16x32_bf16(ones8, ap1, accL, 0, 0, 0);
        __builtin_amdgcn_s_setprio(0);

        // next tile's loads have had the whole body to land
        asm volatile("s_waitcnt vmcnt(0)" ::: "memory");
        __builtin_amdgcn_s_barrier();
        __builtin_amdgcn_sched_barrier(0);
    }

    const float inv = 1.0f / accL[0];                // full K-sum for q-row fr

#pragma unroll
    for (int nt = 0; nt < 4; ++nt) {
        union { __hip_bfloat162 h2[2]; unsigned long long u; } ok;
        ok.h2[0] = __float22bfloat162_rn(make_float2(accT[nt][0] * inv, accT[nt][1] * inv));
        ok.h2[1] = __float22bfloat162_rn(make_float2(accT[nt][2] * inv, accT[nt][3] * inv));
        *(unsigned long long*)&Pw[fr * 72 + nt * 16 + qd * 4] = ok.u;
    }
    {
        const int row = lane >> 2, d0 = (lane & 3) * 16;
        const bf16x8 o0 = *(const bf16x8*)&Pw[row * 72 + d0];
        const bf16x8 o1 = *(const bf16x8*)&Pw[row * 72 + d0 + 8];
        unsigned short* op = attb + ((size_t)b * T_ + qr0 + row) * C_ + h * 64 + d0;
        *(bf16x8*)op = o0;
        *(bf16x8*)(op + 8) = o1;
    }
}

// ---------------------------------------------------------------------------
// Fallback (ws too small for kb): per-wave kernel, fp32 K + tiled V^T.
// NOTE: qb is pre-scaled, so exp2 takes s4 directly (no sc2 mul).
// ---------------------------------------------------------------------------
__global__ __launch_bounds__(256)
void attn_v4(const unsigned short* __restrict__ qb, const float* __restrict__ kf,
             const unsigned short* __restrict__ vtt, unsigned short* __restrict__ attb)
{
    __shared__ alignas(16) unsigned short Pt[4][16 * 72];

    const int tid = threadIdx.x;
    const int lane = tid & 63, w = tid >> 6;
    const int fr = lane & 15, qd = lane >> 4;

    const int blk = blockIdx.x;
    const int xcd = blk & 7, within = blk >> 3;
    const int bh = xcd * 4 + (within & 3);
    const int jj = within >> 2;
    const int kk_ = jj >> 3, ii_ = jj & 7;
    const int qt = (kk_ == 0) ? (31 - ii_) : (kk_ == 1) ? ii_
                 : (kk_ == 2) ? (23 - ii_) : (8 + ii_);
    const int b = bh >> 4, h = bh & 15;

    unsigned short* Pw = Pt[w];
    const unsigned short* qB = qb  + (size_t)bh * T_ * D_;
    const float*          kB = kf  + (size_t)bh * T_ * D_;
    const unsigned short* vT = vtt + (size_t)bh * (T_ / 64) * 64 * 64;

    const int qr0 = qt * 64 + w * 16;
    const int qrow_g = qr0 + fr;

    bf16x8 aq0 = *(const bf16x8*)(qB + (size_t)(qr0 + fr) * D_ + qd * 8);
    bf16x8 aq1 = *(const bf16x8*)(qB + (size_t)(qr0 + fr) * D_ + 32 + qd * 8);

    f32x4 accT[4] = {};
    float l_i = 0.0f;

    for (int jt = 0; jt <= qt; ++jt) {
        bf16x8 bk[8];
#pragma unroll
        for (int q8 = 0; q8 < 8; ++q8) {
            const float* p = kB + (size_t)(jt * 64 + (q8 >> 1) * 16 + fr) * D_
                           + (q8 & 1) * 32 + qd * 8;
            bk[q8] = cvt8(*(const float4*)p, *(const float4*)(p + 4));
        }
        f32x4 s4[4] = {};
#pragma unroll
        for (int nt = 0; nt < 4; ++nt) {
            s4[nt] = __builtin_amdgcn_mfma_f32_16x16x32_bf16(bk[nt * 2 + 0], aq0, s4[nt], 0, 0, 0);
            s4[nt] = __builtin_amdgcn_mfma_f32_16x16x32_bf16(bk[nt * 2 + 1], aq1, s4[nt], 0, 0, 0);
        }
        if (jt == qt) {
            const int kbase = jt * 64 + qd * 4;
#pragma unroll
            for (int nt = 0; nt < 4; ++nt)
#pragma unroll
            for (int r = 0; r < 4; ++r) {
                const int kcol = kbase + nt * 16 + r;
                const float pv = (kcol <= qrow_g)
                               ? __builtin_amdgcn_exp2f(s4[nt][r]) : 0.0f;
                s4[nt][r] = pv; l_i += pv;
            }
        } else {
#pragma unroll
            for (int nt = 0; nt < 4; ++nt)
#pragma unroll
            for (int r = 0; r < 4; ++r) {
                const float pv = __builtin_amdgcn_exp2f(s4[nt][r]);
                s4[nt][r] = pv; l_i += pv;
            }
        }
#pragma unroll
        for (int nt = 0; nt < 4; ++nt) {
            union { __hip_bfloat162 h2[2]; unsigned long long u; } pk;
            pk.h2[0] = __float22bfloat162_rn(make_float2(s4[nt][0], s4[nt][1]));
            pk.h2[1] = __float22bfloat162_rn(make_float2(s4[nt][2], s4[nt][3]));
            *(unsigned long long*)&Pw[fr * 72 + nt * 16 + qd * 4] = pk.u;
        }
        const bf16x8 ap0 = *(const bf16x8*)&Pw[fr * 72 + qd * 8];
        const bf16x8 ap1 = *(const bf16x8*)&Pw[fr * 72 + 32 + qd * 8];

        bf16x8 bv[8];
#pragma unroll
        for (int q8 = 0; q8 < 8; ++q8)
            bv[q8] = *(const bf16x8*)(vT + (size_t)jt * 4096
                                      + ((q8 >> 1) * 16 + fr) * 64 + (q8 & 1) * 32 + qd * 8);
#pragma unroll
        for (int nt = 0; nt < 4; ++nt) {
            accT[nt] = __builtin_amdgcn_mfma_f32_16x16x32_bf16(bv[nt * 2 + 0], ap0, accT[nt], 0, 0, 0);
            accT[nt] = __builtin_amdgcn_mfma_f32_16x16x32_bf16(bv[nt * 2 + 1], ap1, accT[nt], 0, 0, 0);
        }
    }

    l_i += __shfl_xor(l_i, 16);
    l_i += __shfl_xor(l_i, 32);
    const float inv = 1.0f / l_i;
#pragma unroll
    for (int nt = 0; nt < 4; ++nt) {
        union { __hip_bfloat162 h2[2]; unsigned long long u; } ok;
        ok.h2[0] = __float22bfloat162_rn(make_float2(accT[nt][0] * inv, accT[nt][1] * inv));
        ok.h2[1] = __float22bfloat162_rn(make_float2(accT[nt][2] * inv, accT[nt][3] * inv));
        *(unsigned long long*)&Pw[fr * 72 + nt * 16 + qd * 4] = ok.u;
    }
    {
        const int row = lane >> 2, d0 = (lane & 3) * 16;
        const bf16x8 o0 = *(const bf16x8*)&Pw[row * 72 + d0];
        const bf16x8 o1 = *(const bf16x8*)&Pw[row * 72 + d0 + 8];
        unsigned short* op = attb + ((size_t)b * T_ + qr0 + row) * C_ + h * 64 + d0;
        *(bf16x8*)op = o0;
        *(bf16x8*)(op + 8) = o1;
    }
}

// ---------------------------------------------------------------------------
extern "C" void kernel_launch(void* const* d_in, const int* in_sizes, int n_in,
                              void* d_out, int out_size, void* d_ws, size_t ws_size,
                              hipStream_t stream)
{
    (void)in_sizes; (void)n_in; (void)out_size;
    const float* x  = (const float*)d_in[0];
    const float* Wq = (const float*)d_in[1];
    const float* Wk = (const float*)d_in[2];
    const float* Wv = (const float*)d_in[3];
    const float* Wo = (const float*)d_in[4];
    const float* bo = (const float*)d_in[5];

    float* out  = (float*)d_out;                       // (B,T,C)
    float* kout = out  + (size_t)M_ * C_;              // (B,H,T,D) fp32
    float* vout = kout + (size_t)B_ * H_ * T_ * D_;    // (B,H,T,D) fp32

    // ws: xb(8M) | wtb(8M) | qb(8M) | vtt(8M) | kb(8M, optional); attb aliases xb
    unsigned short* xb   = (unsigned short*)d_ws;
    unsigned short* wtb  = xb  + (size_t)M_ * C_;
    unsigned short* qb   = wtb + (size_t)4 * C_ * C_;
    unsigned short* vtt  = qb  + (size_t)M_ * C_;
    unsigned short* kb   = vtt + (size_t)M_ * C_;
    unsigned short* attb = xb;
    const bool use_kb = ws_size >= (size_t)40 * 1024 * 1024;

    prep<<<dim3(16, 16, 5), 256, 0, stream>>>(x, Wq, Wk, Wv, Wo, xb, wtb);

    if (use_kb)
        gemm_qkv<1><<<dim3(16, 32), 512, 0, stream>>>(xb, wtb, qb, kout, vout, kb, vtt);
    else
        gemm_qkv<0><<<dim3(16, 32), 512, 0, stream>>>(xb, wtb, qb, kout, vout, kb, vtt);

    if (use_kb)
        attn_lds<<<1024, 256, 0, stream>>>(qb, kb, vtt, attb);
    else
        attn_v4<<<1024, 256, 0, stream>>>(qb, kout, vtt, attb);

    gemm_o<<<dim3(8, 32), 512, 0, stream>>>(attb, wtb + (size_t)3 * C_ * C_, bo, out);
}